// Round 1
// baseline (736.685 us; speedup 1.0000x reference)
//
#include <hip/hip_runtime.h>
#include <math.h>

#define N 4096
#define NFEAT 512
#define HID 128
#define NHEAD 4
#define DH 32
#define NC 16
#define FF 256

#define BN 64
#define BM 32
#define NCHUNK 8
#define CHUNKM (N / NCHUNK)   // 512

// ---------------------------------------------------------------- K1: feat encoder
__global__ __launch_bounds__(256) void k_feat(const float* __restrict__ x,
    const float* __restrict__ w1, const float* __restrict__ b1,
    const float* __restrict__ w2, const float* __restrict__ b2,
    float* __restrict__ h) {
  __shared__ float xs[16][NFEAT];   // 32KB
  __shared__ float h1s[16][HID];    // 8KB
  int r0 = blockIdx.x * 16, tid = threadIdx.x;
  for (int i = tid; i < 16 * (NFEAT / 4); i += 256) {
    int rr = i >> 7, c4 = i & 127;
    ((float4*)xs[rr])[c4] = *(const float4*)(x + (size_t)(r0 + rr) * NFEAT + c4 * 4);
  }
  __syncthreads();
  int c = tid & 127, rb = tid >> 7;
  float acc[8];
#pragma unroll
  for (int i = 0; i < 8; ++i) acc[i] = b1[c];
  for (int k2 = 0; k2 < NFEAT; ++k2) {
    float wv = w1[k2 * HID + c];
#pragma unroll
    for (int i = 0; i < 8; ++i) acc[i] += xs[rb + 2 * i][k2] * wv;
  }
#pragma unroll
  for (int i = 0; i < 8; ++i) h1s[rb + 2 * i][c] = fmaxf(acc[i], 0.f);
  __syncthreads();
  int rr = tid >> 4, cc = tid & 15;
  float a2 = b2[cc];
  for (int k2 = 0; k2 < HID; ++k2)
    a2 += h1s[rr][k2] * w2[k2 * NC + cc];
  h[(size_t)(r0 + rr) * NC + cc] = a2;
}

// ---------------------------------------------------------------- K2: sine encoding + eig_w
__global__ __launch_bounds__(256) void k_sine_eigw(const float* __restrict__ e,
    const float* __restrict__ eww, const float* __restrict__ ewb,
    float* __restrict__ sc, float* __restrict__ eigw) {
  __shared__ float scs[16][HID];
  __shared__ float es[16];
  int r0 = blockIdx.x * 16, tid = threadIdx.x;
  if (tid < 16) es[tid] = e[r0 + tid];
  __syncthreads();
  for (int i = tid; i < 16 * 64; i += 256) {
    int rr = i >> 6, j = i & 63;
    float div = expf((float)(2 * j) * (-0.07195578415606394f)); // -ln(10000)/128
    float e100 = es[rr] * 100.0f;
    float pe = e100 * div;
    scs[rr][j]      = sinf(pe);
    scs[rr][j + 64] = cosf(pe);
  }
  __syncthreads();
  for (int i = tid; i < 16 * 32; i += 256) {
    int rr = i >> 5, c4 = i & 31;
    *(float4*)(sc + (size_t)(r0 + rr) * HID + c4 * 4) = ((float4*)scs[rr])[c4];
  }
  int c = tid & 127, rb = tid >> 7;
  float acc[8];
#pragma unroll
  for (int i = 0; i < 8; ++i) acc[i] = ewb[c] + es[rb + 2 * i] * eww[c];
  for (int k2 = 0; k2 < HID; ++k2) {
    float wv = eww[(1 + k2) * HID + c];
#pragma unroll
    for (int i = 0; i < 8; ++i) acc[i] += scs[rb + 2 * i][k2] * wv;
  }
#pragma unroll
  for (int i = 0; i < 8; ++i)
    eigw[(size_t)(r0 + rb + 2 * i) * HID + c] = acc[i];
}

// ---------------------------------------------------------------- LayerNorm (1 wave / row)
__global__ __launch_bounds__(256) void k_ln(const float* __restrict__ in,
    const float* __restrict__ g, const float* __restrict__ b, float* __restrict__ out) {
  int row = blockIdx.x * 4 + (threadIdx.x >> 6);
  int l = threadIdx.x & 63;
  float2 v2 = *(const float2*)(in + (size_t)row * HID + l * 2);
  float s = v2.x + v2.y;
  float ss = v2.x * v2.x + v2.y * v2.y;
#pragma unroll
  for (int off = 32; off > 0; off >>= 1) {
    s  += __shfl_down(s, off, 64);
    ss += __shfl_down(ss, off, 64);
  }
  s = __shfl(s, 0, 64); ss = __shfl(ss, 0, 64);
  float mean = s * (1.0f / HID);
  float var = ss * (1.0f / HID) - mean * mean;
  float inv = 1.0f / sqrtf(var + 1e-5f);
  float2 g2 = *(const float2*)(g + l * 2);
  float2 b2 = *(const float2*)(b + l * 2);
  float2 o;
  o.x = (v2.x - mean) * inv * g2.x + b2.x;
  o.y = (v2.y - mean) * inv * g2.y + b2.y;
  *(float2*)(out + (size_t)row * HID + l * 2) = o;
}

// ---------------------------------------------------------------- generic [*,128]@[128,128] (+bias, opt residual)
template <bool RES>
__global__ __launch_bounds__(256) void k_lin128(const float* __restrict__ in,
    const float* __restrict__ w, const float* __restrict__ bias,
    const float* __restrict__ res, float* __restrict__ out) {
  __shared__ float as[16][HID];
  int r0 = blockIdx.x * 16, tid = threadIdx.x;
  for (int i = tid; i < 16 * 32; i += 256) {
    int rr = i >> 5, c4 = i & 31;
    ((float4*)as[rr])[c4] = *(const float4*)(in + (size_t)(r0 + rr) * HID + c4 * 4);
  }
  __syncthreads();
  int c = tid & 127, rb = tid >> 7;
  float acc[8];
#pragma unroll
  for (int i = 0; i < 8; ++i) acc[i] = bias[c];
  for (int k2 = 0; k2 < HID; ++k2) {
    float wv = w[k2 * HID + c];
#pragma unroll
    for (int i = 0; i < 8; ++i) acc[i] += as[rb + 2 * i][k2] * wv;
  }
#pragma unroll
  for (int i = 0; i < 8; ++i) {
    int rr = rb + 2 * i;
    float o = acc[i];
    if (RES) o += res[(size_t)(r0 + rr) * HID + c];
    out[(size_t)(r0 + rr) * HID + c] = o;
  }
}

// ---------------------------------------------------------------- fused flash attention partial (per m-chunk)
__global__ __launch_bounds__(256, 2) void k_attn_partial(
    const float* __restrict__ q, const float* __restrict__ kmat,
    const float* __restrict__ vmat, const float* __restrict__ sc,
    float* __restrict__ pacc, float* __restrict__ pm, float* __restrict__ pl) {
  __shared__ float k_s[BM][HID];          // 16KB
  __shared__ float v_s[BM][HID];          // 16KB
  __shared__ float scm_s[BM][HID + 2];    // 16.25KB (pad 2: conflict-free float2)
  __shared__ float rel_s[BN][BM + 1];     // 8.25KB
  int n0 = blockIdx.x * BN;
  int chunk = blockIdx.y;
  int tid = threadIdx.x;
  int h = tid >> 6;   // wave = head -> all k/v LDS reads are wave-broadcast
  int r = tid & 63;   // row within n-block

  float qreg[DH];
  {
    const float* qp = q + (size_t)(n0 + r) * HID + h * DH;
#pragma unroll
    for (int d = 0; d < DH; d += 4) {
      float4 t = *(const float4*)(qp + d);
      qreg[d] = t.x; qreg[d + 1] = t.y; qreg[d + 2] = t.z; qreg[d + 3] = t.w;
    }
  }
  float acc[DH];
#pragma unroll
  for (int d = 0; d < DH; ++d) acc[d] = 0.f;
  float m_run = -3.0e38f, l_run = 0.f;

  int rb = tid >> 3;  // 0..31 -> rows 2rb,2rb+1 (phase A)
  int mb = tid & 7;   // 0..7  -> cols 4mb..4mb+3 (phase A)
  const float scale = 0.17677669529663687f;  // 1/sqrt(32)

  for (int mt = 0; mt < CHUNKM / BM; ++mt) {
    int m0 = chunk * CHUNKM + mt * BM;
    __syncthreads();
    for (int i = tid; i < BM * 32; i += 256) {
      int row = i >> 5, c4 = i & 31;
      ((float4*)k_s[row])[c4] = *(const float4*)(kmat + (size_t)(m0 + row) * HID + c4 * 4);
      ((float4*)v_s[row])[c4] = *(const float4*)(vmat + (size_t)(m0 + row) * HID + c4 * 4);
    }
    for (int i = tid; i < BM * 32; i += 256) {
      int row = i >> 5, c4 = i & 31;
      float4 t = *(const float4*)(sc + (size_t)(m0 + row) * HID + c4 * 4);
      scm_s[row][c4 * 4 + 0] = t.x; scm_s[row][c4 * 4 + 1] = t.y;
      scm_s[row][c4 * 4 + 2] = t.z; scm_s[row][c4 * 4 + 3] = t.w;
    }
    __syncthreads();
    // phase A: rel tile (shared across heads), 2x4 register block per thread
    {
      float a00 = 0, a01 = 0, a02 = 0, a03 = 0;
      float a10 = 0, a11 = 0, a12 = 0, a13 = 0;
      const float* sn0 = sc + (size_t)(n0 + 2 * rb) * HID;
      const float* sn1 = sn0 + HID;
      for (int d = 0; d < HID; d += 2) {
        float2 x0 = *(const float2*)(sn0 + d);
        float2 x1 = *(const float2*)(sn1 + d);
        float2 y0 = *(const float2*)(&scm_s[4 * mb + 0][d]);
        float2 y1 = *(const float2*)(&scm_s[4 * mb + 1][d]);
        float2 y2 = *(const float2*)(&scm_s[4 * mb + 2][d]);
        float2 y3 = *(const float2*)(&scm_s[4 * mb + 3][d]);
        a00 += x0.x * y0.x + x0.y * y0.y;  a10 += x1.x * y0.x + x1.y * y0.y;
        a01 += x0.x * y1.x + x0.y * y1.y;  a11 += x1.x * y1.x + x1.y * y1.y;
        a02 += x0.x * y2.x + x0.y * y2.y;  a12 += x1.x * y2.x + x1.y * y2.y;
        a03 += x0.x * y3.x + x0.y * y3.y;  a13 += x1.x * y3.x + x1.y * y3.y;
      }
      rel_s[2 * rb + 0][4 * mb + 0] = a00; rel_s[2 * rb + 0][4 * mb + 1] = a01;
      rel_s[2 * rb + 0][4 * mb + 2] = a02; rel_s[2 * rb + 0][4 * mb + 3] = a03;
      rel_s[2 * rb + 1][4 * mb + 0] = a10; rel_s[2 * rb + 1][4 * mb + 1] = a11;
      rel_s[2 * rb + 1][4 * mb + 2] = a12; rel_s[2 * rb + 1][4 * mb + 3] = a13;
    }
    __syncthreads();
    // phase B: per-head scores + online softmax + PV
    float sv[BM];
    float tilemax = -3.0e38f;
#pragma unroll
    for (int mm = 0; mm < BM; ++mm) {
      float a0 = 0, a1 = 0, a2 = 0, a3 = 0;
      const float* kp = &k_s[mm][h * DH];
#pragma unroll
      for (int d = 0; d < DH; d += 4) {
        float4 k4 = *(const float4*)(kp + d);
        a0 += qreg[d] * k4.x;  a1 += qreg[d + 1] * k4.y;
        a2 += qreg[d + 2] * k4.z;  a3 += qreg[d + 3] * k4.w;
      }
      float sval = (((a0 + a1) + (a2 + a3)) + rel_s[r][mm]) * scale;
      sv[mm] = sval;
      tilemax = fmaxf(tilemax, sval);
    }
    float newm = fmaxf(m_run, tilemax);
    float corr = __expf(m_run - newm);
    m_run = newm;
    l_run *= corr;
#pragma unroll
    for (int d = 0; d < DH; ++d) acc[d] *= corr;
#pragma unroll
    for (int mm = 0; mm < BM; ++mm) {
      float p = __expf(sv[mm] - newm);
      l_run += p;
      const float* vp = &v_s[mm][h * DH];
#pragma unroll
      for (int d = 0; d < DH; d += 4) {
        float4 v4 = *(const float4*)(vp + d);
        acc[d]     += p * v4.x;  acc[d + 1] += p * v4.y;
        acc[d + 2] += p * v4.z;  acc[d + 3] += p * v4.w;
      }
    }
  }
  size_t base = (size_t)chunk * N + n0 + r;
  float* pa = pacc + base * HID + h * DH;
#pragma unroll
  for (int d = 0; d < DH; d += 4) {
    float4 t; t.x = acc[d]; t.y = acc[d + 1]; t.z = acc[d + 2]; t.w = acc[d + 3];
    *(float4*)(pa + d) = t;
  }
  pm[base * NHEAD + h] = m_run;
  pl[base * NHEAD + h] = l_run;
}

// ---------------------------------------------------------------- merge attention partials
__global__ __launch_bounds__(256) void k_attn_merge(
    const float* __restrict__ pacc, const float* __restrict__ pm,
    const float* __restrict__ pl, float* __restrict__ out) {
  int idx = blockIdx.x * 256 + threadIdx.x;  // n*NHEAD + h
  int n_ = idx >> 2, h = idx & 3;
  float mx = -3.0e38f;
#pragma unroll
  for (int c = 0; c < NCHUNK; ++c)
    mx = fmaxf(mx, pm[((size_t)c * N + n_) * NHEAD + h]);
  float w[NCHUNK];
  float L = 0.f;
#pragma unroll
  for (int c = 0; c < NCHUNK; ++c) {
    float wc = __expf(pm[((size_t)c * N + n_) * NHEAD + h] - mx);
    w[c] = wc;
    L += pl[((size_t)c * N + n_) * NHEAD + h] * wc;
  }
  float invL = 1.0f / L;
  float* op = out + (size_t)n_ * HID + h * DH;
#pragma unroll
  for (int d = 0; d < DH; d += 4) {
    float sx = 0, sy = 0, sz = 0, sw = 0;
#pragma unroll
    for (int c = 0; c < NCHUNK; ++c) {
      float4 t = *(const float4*)(pacc + ((size_t)c * N + n_) * HID + h * DH + d);
      sx += w[c] * t.x; sy += w[c] * t.y; sz += w[c] * t.z; sw += w[c] * t.w;
    }
    float4 o; o.x = sx * invL; o.y = sy * invL; o.z = sz * invL; o.w = sw * invL;
    *(float4*)(op + d) = o;
  }
}

// ---------------------------------------------------------------- FFN fused (LN output in, +residual out)
__global__ __launch_bounds__(256) void k_ffn(const float* __restrict__ fln,
    const float* __restrict__ w1, const float* __restrict__ b1,
    const float* __restrict__ w2, const float* __restrict__ b2,
    const float* __restrict__ eig, float* __restrict__ out) {
  __shared__ float fs[16][HID];
  __shared__ float t1[16][FF];
  int r0 = blockIdx.x * 16, tid = threadIdx.x;
  for (int i = tid; i < 16 * 32; i += 256) {
    int rr = i >> 5, c4 = i & 31;
    ((float4*)fs[rr])[c4] = *(const float4*)(fln + (size_t)(r0 + rr) * HID + c4 * 4);
  }
  __syncthreads();
  {
    float acc[16];
#pragma unroll
    for (int i = 0; i < 16; ++i) acc[i] = b1[tid];
    for (int k2 = 0; k2 < HID; ++k2) {
      float wv = w1[k2 * FF + tid];
#pragma unroll
      for (int i = 0; i < 16; ++i) acc[i] += fs[i][k2] * wv;
    }
#pragma unroll
    for (int i = 0; i < 16; ++i) {
      float xg = acc[i];
      t1[i][tid] = 0.5f * xg * (1.0f + erff(xg * 0.7071067811865476f));
    }
  }
  __syncthreads();
  int c = tid & 127, rb = tid >> 7;
  float acc2[8];
#pragma unroll
  for (int i = 0; i < 8; ++i) acc2[i] = b2[c];
  for (int k2 = 0; k2 < FF; ++k2) {
    float wv = w2[k2 * HID + c];
#pragma unroll
    for (int i = 0; i < 8; ++i) acc2[i] += t1[rb + 2 * i][k2] * wv;
  }
#pragma unroll
  for (int i = 0; i < 8; ++i) {
    int rr = r0 + rb + 2 * i;
    out[(size_t)rr * HID + c] = acc2[i] + eig[(size_t)rr * HID + c];
  }
}

// ---------------------------------------------------------------- decoder [N,128]@[128,4]
__global__ __launch_bounds__(256) void k_dec(const float* __restrict__ eig2,
    const float* __restrict__ dw, const float* __restrict__ db, float* __restrict__ newe) {
  int idx = blockIdx.x * 256 + threadIdx.x;  // n*4 + j
  int n_ = idx >> 2, j = idx & 3;
  float a = db[j];
  for (int k2 = 0; k2 < HID; ++k2)
    a += eig2[(size_t)n_ * HID + k2] * dw[k2 * NHEAD + j];
  newe[idx] = a;
}

// ---------------------------------------------------------------- utx partials: u^T @ h (n-split x8)
__global__ __launch_bounds__(256) void k_utx(const float* __restrict__ u,
    const float* __restrict__ h, float* __restrict__ putx) {
  int m0 = blockIdx.x * 128;
  int nch = blockIdx.y;  // 0..7
  __shared__ float us[32][128];
  __shared__ float hs[32][NC];
  int tid = threadIdx.x;
  int m_l = tid & 127;
  int c0 = (tid >> 7) * 8;
  float acc[8];
#pragma unroll
  for (int j = 0; j < 8; ++j) acc[j] = 0.f;
  for (int n0 = nch * 512; n0 < nch * 512 + 512; n0 += 32) {
    __syncthreads();
    for (int i = tid; i < 32 * 32; i += 256) {
      int nl = i >> 5, c4 = i & 31;
      ((float4*)us[nl])[c4] = *(const float4*)(u + (size_t)(n0 + nl) * N + m0 + c4 * 4);
    }
    if (tid < 128) {
      int nl = tid >> 2, c4 = tid & 3;
      ((float4*)hs[nl])[c4] = *(const float4*)(h + (size_t)(n0 + nl) * NC + c4 * 4);
    }
    __syncthreads();
    for (int nl = 0; nl < 32; ++nl) {
      float uv = us[nl][m_l];
#pragma unroll
      for (int j = 0; j < 8; ++j) acc[j] += uv * hs[nl][c0 + j];
    }
  }
  float* o = putx + ((size_t)nch * N + m0 + m_l) * NC + c0;
#pragma unroll
  for (int j = 0; j < 8; ++j) o[j] = acc[j];
}

// ---------------------------------------------------------------- s[m,c] = (sum partial utx) * (sum_h newe*specw)
__global__ __launch_bounds__(256) void k_sbuild(const float* __restrict__ putx,
    const float* __restrict__ newe, const float* __restrict__ specw,
    float* __restrict__ s) {
  int idx = blockIdx.x * 256 + threadIdx.x;  // m*NC + c
  int m = idx >> 4, c = idx & 15;
  float t = 0.f;
#pragma unroll
  for (int ch = 0; ch < 8; ++ch) t += putx[((size_t)ch * N + m) * NC + c];
  float fac = 0.f;
#pragma unroll
  for (int hh = 0; hh < NHEAD; ++hh) fac += newe[m * NHEAD + hh] * specw[(1 + hh) * NC + c];
  s[idx] = t * fac;
}

// ---------------------------------------------------------------- out = h*specw0 + u @ s
__global__ __launch_bounds__(256) void k_final(const float* __restrict__ u,
    const float* __restrict__ s, const float* __restrict__ h,
    const float* __restrict__ specw, float* __restrict__ out) {
  __shared__ float us[16][260];   // pad->260: float4-aligned, conflict-free
  __shared__ float ssT[16][260];  // transposed s tile [c][m]
  int n0 = blockIdx.x * 16, tid = threadIdx.x;
  int nl = tid >> 4, c = tid & 15;
  float a0 = 0, a1 = 0, a2 = 0, a3 = 0;
  for (int m0 = 0; m0 < N; m0 += 256) {
    __syncthreads();
    for (int i = tid; i < 16 * 64; i += 256) {
      int rr = i >> 6, c4 = i & 63;
      float4 t = *(const float4*)(u + (size_t)(n0 + rr) * N + m0 + c4 * 4);
      *(float4*)(&us[rr][c4 * 4]) = t;
    }
    for (int i = tid; i < 256 * 4; i += 256) {
      int mm = i >> 2, c4 = i & 3;
      float4 t = *(const float4*)(s + (size_t)(m0 + mm) * NC + c4 * 4);
      ssT[c4 * 4 + 0][mm] = t.x; ssT[c4 * 4 + 1][mm] = t.y;
      ssT[c4 * 4 + 2][mm] = t.z; ssT[c4 * 4 + 3][mm] = t.w;
    }
    __syncthreads();
#pragma unroll 8
    for (int mm = 0; mm < 256; mm += 4) {
      float4 uu = *(const float4*)(&us[nl][mm]);
      float4 s4 = *(const float4*)(&ssT[c][mm]);
      a0 += uu.x * s4.x; a1 += uu.y * s4.y; a2 += uu.z * s4.z; a3 += uu.w * s4.w;
    }
  }
  int n_ = n0 + nl;
  out[(size_t)n_ * NC + c] = (a0 + a1) + (a2 + a3) + h[(size_t)n_ * NC + c] * specw[c];
}

// ================================================================ launcher
extern "C" void kernel_launch(void* const* d_in, const int* in_sizes, int n_in,
                              void* d_out, int out_size, void* d_ws, size_t ws_size,
                              hipStream_t stream) {
  const float* e    = (const float*)d_in[0];
  const float* u    = (const float*)d_in[1];
  const float* x    = (const float*)d_in[2];
  const float* few1 = (const float*)d_in[3];
  const float* feb1 = (const float*)d_in[4];
  const float* few2 = (const float*)d_in[5];
  const float* feb2 = (const float*)d_in[6];
  const float* eww  = (const float*)d_in[7];
  const float* ewb  = (const float*)d_in[8];
  const float* ln1g = (const float*)d_in[9];
  const float* ln1b = (const float*)d_in[10];
  const float* wq   = (const float*)d_in[11];
  const float* bq   = (const float*)d_in[12];
  const float* wk   = (const float*)d_in[13];
  const float* bk   = (const float*)d_in[14];
  const float* wv_  = (const float*)d_in[15];
  const float* bv   = (const float*)d_in[16];
  const float* wo   = (const float*)d_in[17];
  const float* bo   = (const float*)d_in[18];
  const float* ln2g = (const float*)d_in[19];
  const float* ln2b = (const float*)d_in[20];
  const float* fw1  = (const float*)d_in[21];
  const float* fb1  = (const float*)d_in[22];
  const float* fw2  = (const float*)d_in[23];
  const float* fb2  = (const float*)d_in[24];
  const float* dw   = (const float*)d_in[25];
  const float* db   = (const float*)d_in[26];
  const float* spw  = (const float*)d_in[27];
  float* out = (float*)d_out;

  float* ws = (float*)d_ws;
  float* h    = ws;  ws += N * NC;
  float* sc   = ws;  ws += N * HID;
  float* eigw = ws;  ws += N * HID;
  float* mln  = ws;  ws += N * HID;
  float* q    = ws;  ws += N * HID;
  float* k    = ws;  ws += N * HID;
  float* v    = ws;  ws += N * HID;
  float* attno= ws;  ws += N * HID;
  float* eig  = ws;  ws += N * HID;
  float* fln  = ws;  ws += N * HID;
  float* eig2 = ws;  ws += N * HID;
  float* newe = ws;  ws += N * NHEAD;
  float* sarr = ws;  ws += N * NC;
  float* pacc = ws;  ws += (size_t)NCHUNK * N * HID;
  float* pm   = ws;  ws += (size_t)NCHUNK * N * NHEAD;
  float* pl   = ws;  ws += (size_t)NCHUNK * N * NHEAD;
  float* putx = ws;  ws += (size_t)8 * N * NC;

  k_feat<<<N / 16, 256, 0, stream>>>(x, few1, feb1, few2, feb2, h);
  k_sine_eigw<<<N / 16, 256, 0, stream>>>(e, eww, ewb, sc, eigw);
  k_ln<<<N / 4, 256, 0, stream>>>(eigw, ln1g, ln1b, mln);
  k_lin128<false><<<N / 16, 256, 0, stream>>>(mln, wq, bq, nullptr, q);
  k_lin128<false><<<N / 16, 256, 0, stream>>>(mln, wk, bk, nullptr, k);
  k_lin128<false><<<N / 16, 256, 0, stream>>>(mln, wv_, bv, nullptr, v);
  k_attn_partial<<<dim3(N / BN, NCHUNK), 256, 0, stream>>>(q, k, v, sc, pacc, pm, pl);
  k_attn_merge<<<N * NHEAD / 256, 256, 0, stream>>>(pacc, pm, pl, attno);
  k_lin128<true><<<N / 16, 256, 0, stream>>>(attno, wo, bo, eigw, eig);
  k_ln<<<N / 4, 256, 0, stream>>>(eig, ln2g, ln2b, fln);
  k_ffn<<<N / 16, 256, 0, stream>>>(fln, fw1, fb1, fw2, fb2, eig, eig2);
  k_dec<<<N * NHEAD / 256, 256, 0, stream>>>(eig2, dw, db, newe);
  k_utx<<<dim3(N / 128, 8), 256, 0, stream>>>(u, h, putx);
  k_sbuild<<<N * NC / 256, 256, 0, stream>>>(putx, newe, spw, sarr);
  k_final<<<N / 16, 256, 0, stream>>>(u, sarr, h, spw, out);
}

// Round 2
// 507.322 us; speedup vs baseline: 1.4521x; 1.4521x over previous
//
#include <hip/hip_runtime.h>
#include <math.h>

#define N 4096
#define NFEAT 512
#define HID 128
#define NHEAD 4
#define DH 32
#define NC 16
#define FF 256

typedef _Float16 f16;
typedef unsigned int uint;
typedef _Float16 f16x8 __attribute__((ext_vector_type(8)));
typedef _Float16 f16x2 __attribute__((ext_vector_type(2)));
typedef float f32x16 __attribute__((ext_vector_type(16)));

#define SCALE 0.17677669529663687f      // 1/sqrt(32)
#define LOG2E 1.44269504088896f
#define SH2   (-14.0f * 1.44269504088896f)   // fixed softmax shift of 14 (scores <= ~13.4)

// ---------------------------------------------------------------- K1: feat encoder (unchanged)
__global__ __launch_bounds__(256) void k_feat(const float* __restrict__ x,
    const float* __restrict__ w1, const float* __restrict__ b1,
    const float* __restrict__ w2, const float* __restrict__ b2,
    float* __restrict__ h) {
  __shared__ float xs[16][NFEAT];
  __shared__ float h1s[16][HID];
  int r0 = blockIdx.x * 16, tid = threadIdx.x;
  for (int i = tid; i < 16 * (NFEAT / 4); i += 256) {
    int rr = i >> 7, c4 = i & 127;
    ((float4*)xs[rr])[c4] = *(const float4*)(x + (size_t)(r0 + rr) * NFEAT + c4 * 4);
  }
  __syncthreads();
  int c = tid & 127, rb = tid >> 7;
  float acc[8];
#pragma unroll
  for (int i = 0; i < 8; ++i) acc[i] = b1[c];
  for (int k2 = 0; k2 < NFEAT; ++k2) {
    float wv = w1[k2 * HID + c];
#pragma unroll
    for (int i = 0; i < 8; ++i) acc[i] += xs[rb + 2 * i][k2] * wv;
  }
#pragma unroll
  for (int i = 0; i < 8; ++i) h1s[rb + 2 * i][c] = fmaxf(acc[i], 0.f);
  __syncthreads();
  int rr = tid >> 4, cc = tid & 15;
  float a2 = b2[cc];
  for (int k2 = 0; k2 < HID; ++k2)
    a2 += h1s[rr][k2] * w2[k2 * NC + cc];
  h[(size_t)(r0 + rr) * NC + cc] = a2;
}

// ---------------------------------------------------------------- K2: sine encoding + eig_w + f16 sc outputs
__global__ __launch_bounds__(256) void k_sine_eigw(const float* __restrict__ e,
    const float* __restrict__ eww, const float* __restrict__ ewb,
    f16* __restrict__ sc_h, f16* __restrict__ scS_h, float* __restrict__ eigw) {
  __shared__ float scs[16][HID];
  __shared__ float es[16];
  int r0 = blockIdx.x * 16, tid = threadIdx.x;
  if (tid < 16) es[tid] = e[r0 + tid];
  __syncthreads();
  for (int i = tid; i < 16 * 64; i += 256) {
    int rr = i >> 6, j = i & 63;
    float div = expf((float)(2 * j) * (-0.07195578415606394f)); // -ln(10000)/128
    float pe = es[rr] * 100.0f * div;
    scs[rr][j]      = sinf(pe);
    scs[rr][j + 64] = cosf(pe);
  }
  __syncthreads();
  // f16 outputs: sc_h (raw), scS_h (pre-scaled by SCALE) -- packed dword writes
  for (int i = tid; i < 16 * 64; i += 256) {
    int rr = i >> 6, jj = i & 63;
    float x0 = scs[rr][2 * jj], x1 = scs[rr][2 * jj + 1];
    f16x2 a; a[0] = (f16)x0; a[1] = (f16)x1;
    f16x2 b; b[0] = (f16)(x0 * SCALE); b[1] = (f16)(x1 * SCALE);
    ((f16x2*)sc_h)[(size_t)(r0 + rr) * 64 + jj] = a;
    ((f16x2*)scS_h)[(size_t)(r0 + rr) * 64 + jj] = b;
  }
  int c = tid & 127, rb = tid >> 7;
  float acc[8];
#pragma unroll
  for (int i = 0; i < 8; ++i) acc[i] = ewb[c] + es[rb + 2 * i] * eww[c];
  for (int k2 = 0; k2 < HID; ++k2) {
    float wv = eww[(1 + k2) * HID + c];
#pragma unroll
    for (int i = 0; i < 8; ++i) acc[i] += scs[rb + 2 * i][k2] * wv;
  }
#pragma unroll
  for (int i = 0; i < 8; ++i)
    eigw[(size_t)(r0 + rb + 2 * i) * HID + c] = acc[i];
}

// ---------------------------------------------------------------- LayerNorm (unchanged)
__global__ __launch_bounds__(256) void k_ln(const float* __restrict__ in,
    const float* __restrict__ g, const float* __restrict__ b, float* __restrict__ out) {
  int row = blockIdx.x * 4 + (threadIdx.x >> 6);
  int l = threadIdx.x & 63;
  float2 v2 = *(const float2*)(in + (size_t)row * HID + l * 2);
  float s = v2.x + v2.y;
  float ss = v2.x * v2.x + v2.y * v2.y;
#pragma unroll
  for (int off = 32; off > 0; off >>= 1) {
    s  += __shfl_down(s, off, 64);
    ss += __shfl_down(ss, off, 64);
  }
  s = __shfl(s, 0, 64); ss = __shfl(ss, 0, 64);
  float mean = s * (1.0f / HID);
  float var = ss * (1.0f / HID) - mean * mean;
  float inv = 1.0f / sqrtf(var + 1e-5f);
  float2 g2 = *(const float2*)(g + l * 2);
  float2 b2 = *(const float2*)(b + l * 2);
  float2 o;
  o.x = (v2.x - mean) * inv * g2.x + b2.x;
  o.y = (v2.y - mean) * inv * g2.y + b2.y;
  *(float2*)(out + (size_t)row * HID + l * 2) = o;
}

// ---------------------------------------------------------------- [*,128]@[128,128] (+bias, opt residual, opt f16 out)
template <bool RES, bool F16O>
__global__ __launch_bounds__(256) void k_lin128(const float* __restrict__ in,
    const float* __restrict__ w, const float* __restrict__ bias,
    const float* __restrict__ res, float* __restrict__ out, f16* __restrict__ outh,
    float oscale) {
  __shared__ float as[16][HID];
  int r0 = blockIdx.x * 16, tid = threadIdx.x;
  for (int i = tid; i < 16 * 32; i += 256) {
    int rr = i >> 5, c4 = i & 31;
    ((float4*)as[rr])[c4] = *(const float4*)(in + (size_t)(r0 + rr) * HID + c4 * 4);
  }
  __syncthreads();
  int c = tid & 127, rb = tid >> 7;
  float acc[8];
#pragma unroll
  for (int i = 0; i < 8; ++i) acc[i] = bias[c];
  for (int k2 = 0; k2 < HID; ++k2) {
    float wv = w[k2 * HID + c];
#pragma unroll
    for (int i = 0; i < 8; ++i) acc[i] += as[rb + 2 * i][k2] * wv;
  }
#pragma unroll
  for (int i = 0; i < 8; ++i) {
    int rr = rb + 2 * i;
    float o = acc[i];
    if (RES) o += res[(size_t)(r0 + rr) * HID + c];
    if (F16O) outh[(size_t)(r0 + rr) * HID + c] = (f16)(o * oscale);
    else      out[(size_t)(r0 + rr) * HID + c] = o;
  }
}

// ---------------------------------------------------------------- v (f32) -> vT (f16, [128][N])
__global__ __launch_bounds__(256) void k_vT(const float* __restrict__ v, f16* __restrict__ vT) {
  __shared__ float vs[64][132];
  int n0 = blockIdx.x * 64, tid = threadIdx.x;
  for (int i = tid; i < 64 * 32; i += 256) {
    int r = i >> 5, c4 = i & 31;
    *(float4*)&vs[r][c4 * 4] = *(const float4*)(v + (size_t)(n0 + r) * HID + c4 * 4);
  }
  __syncthreads();
  for (int i = tid; i < 128 * 32; i += 256) {   // dword units: d row, j = n-pair
    int d = i >> 5, j = i & 31;
    f16x2 hh; hh[0] = (f16)vs[2 * j][d]; hh[1] = (f16)vs[2 * j + 1][d];
    ((f16x2*)vT)[((size_t)d * N + n0) / 2 + j] = hh;
  }
}

// ---------------------------------------------------------------- rel GEMM: scale*(sc@scT), fragment-order output
// C-frag layout (32x32): col = lane&31, row = (reg&3)+8*(reg>>2)+4*(lane>>5). rel symmetric ->
// attention reads frag [mtile][ntile] as S^T init. Zero LDS; all operands global (L2-hot, ~130MB total).
template <bool R32>
__global__ __launch_bounds__(256) void k_relgemm(const f16* __restrict__ scS, const f16* __restrict__ sc,
    void* __restrict__ relf) {
  int tid = threadIdx.x, w = tid >> 6, lane = tid & 63, lrow = lane & 31, lhalf = lane >> 5;
  int wr = w >> 1, wc = w & 1;
  int arow0 = blockIdx.x * 128 + wr * 64;
  int brow0 = blockIdx.y * 128 + wc * 64;
  f32x16 acc00 = {0,0,0,0,0,0,0,0,0,0,0,0,0,0,0,0};
  f32x16 acc01 = acc00, acc10 = acc00, acc11 = acc00;
#pragma unroll
  for (int ks = 0; ks < 8; ++ks) {
    f16x8 a0 = *(const f16x8*)(scS + (size_t)(arow0 + lrow) * HID + ks * 16 + lhalf * 8);
    f16x8 a1 = *(const f16x8*)(scS + (size_t)(arow0 + 32 + lrow) * HID + ks * 16 + lhalf * 8);
    f16x8 b0 = *(const f16x8*)(sc + (size_t)(brow0 + lrow) * HID + ks * 16 + lhalf * 8);
    f16x8 b1 = *(const f16x8*)(sc + (size_t)(brow0 + 32 + lrow) * HID + ks * 16 + lhalf * 8);
    acc00 = __builtin_amdgcn_mfma_f32_32x32x16_f16(a0, b0, acc00, 0, 0, 0);
    acc01 = __builtin_amdgcn_mfma_f32_32x32x16_f16(a0, b1, acc01, 0, 0, 0);
    acc10 = __builtin_amdgcn_mfma_f32_32x32x16_f16(a1, b0, acc10, 0, 0, 0);
    acc11 = __builtin_amdgcn_mfma_f32_32x32x16_f16(a1, b1, acc11, 0, 0, 0);
  }
  int at0 = arow0 >> 5, bt0 = brow0 >> 5;
#pragma unroll
  for (int nf = 0; nf < 2; ++nf) {
#pragma unroll
    for (int mf = 0; mf < 2; ++mf) {
      const f32x16& A = nf == 0 ? (mf == 0 ? acc00 : acc01) : (mf == 0 ? acc10 : acc11);
      size_t fidx = (size_t)(at0 + nf) * 128 + (bt0 + mf);
      if (R32) {
        float* op = (float*)relf + fidx * 1024 + lane * 16;
        *(float4*)(op +  0) = make_float4(A[0],  A[1],  A[2],  A[3]);
        *(float4*)(op +  4) = make_float4(A[4],  A[5],  A[6],  A[7]);
        *(float4*)(op +  8) = make_float4(A[8],  A[9],  A[10], A[11]);
        *(float4*)(op + 12) = make_float4(A[12], A[13], A[14], A[15]);
      } else {
        uint* op = (uint*)relf + fidx * 512 + lane * 8;
        uint u[8];
#pragma unroll
        for (int i = 0; i < 8; ++i) {
          f16x2 hh; hh[0] = (f16)A[2 * i]; hh[1] = (f16)A[2 * i + 1];
          u[i] = __builtin_bit_cast(uint, hh);
        }
        *(uint4*)(op) = make_uint4(u[0], u[1], u[2], u[3]);
        *(uint4*)(op + 4) = make_uint4(u[4], u[5], u[6], u[7]);
      }
    }
  }
}

// ---------------------------------------------------------------- fused MFMA flash attention (zero LDS)
// 4 waves = 4 heads, n-tile 32, m-chunk 1024. S^T = relfrag(C-init) + mfma(K,Q); fixed-shift softmax;
// P -> f16 B-frags in-register (cvt_pkrtz + shfl_xor32); O^T += mfma(vT, P).
template <bool R32>
__global__ __launch_bounds__(256) void k_attn2(const f16* __restrict__ qh, const f16* __restrict__ kh,
    const f16* __restrict__ vTh, const void* __restrict__ relf,
    float* __restrict__ pacc, float* __restrict__ pl) {
  int tid = threadIdx.x, h = tid >> 6, lane = tid & 63, lrow = lane & 31, lhalf = lane >> 5;
  int n0 = blockIdx.x * 32, ntile = blockIdx.x, chunk = blockIdx.y;
  const f16* qp = qh + (size_t)(n0 + lrow) * HID + 32 * h + lhalf * 8;
  f16x8 qb0 = *(const f16x8*)(qp);
  f16x8 qb1 = *(const f16x8*)(qp + 16);
  f32x16 oacc = {0,0,0,0,0,0,0,0,0,0,0,0,0,0,0,0};
  float l = 0.f;
  for (int mt = 0; mt < 32; ++mt) {
    int m0 = chunk * 1024 + mt * 32;
    // S^T init from rel fragment (symmetric: stored [mtile][ntile])
    f32x16 sacc;
    size_t fidx = (size_t)(m0 >> 5) * 128 + ntile;
    if (R32) {
      const float* rp = (const float*)relf + fidx * 1024 + lane * 16;
      float4 r0 = *(const float4*)(rp), r1 = *(const float4*)(rp + 4);
      float4 r2 = *(const float4*)(rp + 8), r3 = *(const float4*)(rp + 12);
      sacc[0]=r0.x; sacc[1]=r0.y; sacc[2]=r0.z; sacc[3]=r0.w;
      sacc[4]=r1.x; sacc[5]=r1.y; sacc[6]=r1.z; sacc[7]=r1.w;
      sacc[8]=r2.x; sacc[9]=r2.y; sacc[10]=r2.z; sacc[11]=r2.w;
      sacc[12]=r3.x; sacc[13]=r3.y; sacc[14]=r3.z; sacc[15]=r3.w;
    } else {
      const uint* rp = (const uint*)relf + fidx * 512 + lane * 8;
      uint4 ua = *(const uint4*)(rp), ub = *(const uint4*)(rp + 4);
      uint uu[8] = {ua.x, ua.y, ua.z, ua.w, ub.x, ub.y, ub.z, ub.w};
#pragma unroll
      for (int i = 0; i < 8; ++i) {
        f16x2 hh = __builtin_bit_cast(f16x2, uu[i]);
        sacc[2 * i] = (float)hh[0]; sacc[2 * i + 1] = (float)hh[1];
      }
    }
    // K A-frags + V A-frags (global, L2-hot)
    const f16* kp = kh + (size_t)(m0 + lrow) * HID + 32 * h + lhalf * 8;
    f16x8 ka0 = *(const f16x8*)(kp);
    f16x8 ka1 = *(const f16x8*)(kp + 16);
    const f16* vp = vTh + (size_t)(32 * h + lrow) * N + m0 + lhalf * 8;
    f16x8 va0 = *(const f16x8*)(vp);
    f16x8 va1 = *(const f16x8*)(vp + 16);
    sacc = __builtin_amdgcn_mfma_f32_32x32x16_f16(ka0, qb0, sacc, 0, 0, 0);
    sacc = __builtin_amdgcn_mfma_f32_32x32x16_f16(ka1, qb1, sacc, 0, 0, 0);
    // fixed-shift softmax + in-register P->B-frag packing, per kstep (regs 0..7 then 8..15)
    uint w0[2], w1[2], w2[2], w3[2];
#pragma unroll
    for (int ks = 0; ks < 2; ++ks) {
      float p[8];
#pragma unroll
      for (int i = 0; i < 8; ++i)
        p[i] = exp2f(fmaf(sacc[ks * 8 + i], LOG2E, SH2));
      uint Wa = __builtin_bit_cast(uint, __builtin_amdgcn_cvt_pkrtz(p[0], p[1]));
      uint Wb = __builtin_bit_cast(uint, __builtin_amdgcn_cvt_pkrtz(p[2], p[3]));
      uint Wc = __builtin_bit_cast(uint, __builtin_amdgcn_cvt_pkrtz(p[4], p[5]));
      uint Wd = __builtin_bit_cast(uint, __builtin_amdgcn_cvt_pkrtz(p[6], p[7]));
      // l accumulates the f16-rounded values (exact consistency with PV numerator)
      {
        f16x2 ha = __builtin_bit_cast(f16x2, Wa), hb = __builtin_bit_cast(f16x2, Wb);
        f16x2 hc = __builtin_bit_cast(f16x2, Wc), hd = __builtin_bit_cast(f16x2, Wd);
        l += (float)ha[0] + (float)ha[1] + (float)hb[0] + (float)hb[1]
           + (float)hc[0] + (float)hc[1] + (float)hd[0] + (float)hd[1];
      }
      uint Wax = (uint)__shfl_xor((int)Wa, 32, 64);
      uint Wbx = (uint)__shfl_xor((int)Wb, 32, 64);
      uint Wcx = (uint)__shfl_xor((int)Wc, 32, 64);
      uint Wdx = (uint)__shfl_xor((int)Wd, 32, 64);
      bool hi = (lhalf != 0);
      w0[ks] = hi ? Wcx : Wa;
      w1[ks] = hi ? Wdx : Wb;
      w2[ks] = hi ? Wc : Wax;
      w3[ks] = hi ? Wd : Wbx;
    }
    f16x8 pb0 = __builtin_bit_cast(f16x8, make_uint4(w0[0], w1[0], w2[0], w3[0]));
    f16x8 pb1 = __builtin_bit_cast(f16x8, make_uint4(w0[1], w1[1], w2[1], w3[1]));
    oacc = __builtin_amdgcn_mfma_f32_32x32x16_f16(va0, pb0, oacc, 0, 0, 0);
    oacc = __builtin_amdgcn_mfma_f32_32x32x16_f16(va1, pb1, oacc, 0, 0, 0);
  }
  l += __shfl_xor(l, 32, 64);
  float* pp = pacc + ((size_t)(chunk * 4 + h) * 128 + ntile) * 1024 + lane * 16;
  *(float4*)(pp +  0) = make_float4(oacc[0],  oacc[1],  oacc[2],  oacc[3]);
  *(float4*)(pp +  4) = make_float4(oacc[4],  oacc[5],  oacc[6],  oacc[7]);
  *(float4*)(pp +  8) = make_float4(oacc[8],  oacc[9],  oacc[10], oacc[11]);
  *(float4*)(pp + 12) = make_float4(oacc[12], oacc[13], oacc[14], oacc[15]);
  if (lane < 32) pl[(size_t)(chunk * 4 + h) * N + n0 + lrow] = l;
}

// ---------------------------------------------------------------- merge 4 m-chunks (fixed shift -> plain sums)
__global__ __launch_bounds__(256) void k_attn_merge2(const float* __restrict__ pacc,
    const float* __restrict__ pl, float* __restrict__ attno) {
  __shared__ float ao[32][132];
  int tid = threadIdx.x, h = tid >> 6, lane = tid & 63, lrow = lane & 31, lhalf = lane >> 5;
  int ntile = blockIdx.x, n0 = ntile * 32;
  float o[16];
#pragma unroll
  for (int r = 0; r < 16; ++r) o[r] = 0.f;
  float l = 0.f;
#pragma unroll
  for (int c = 0; c < 4; ++c) {
    const float* pp = pacc + ((size_t)(c * 4 + h) * 128 + ntile) * 1024 + lane * 16;
    float4 r0 = *(const float4*)(pp), r1 = *(const float4*)(pp + 4);
    float4 r2 = *(const float4*)(pp + 8), r3 = *(const float4*)(pp + 12);
    o[0]+=r0.x; o[1]+=r0.y; o[2]+=r0.z; o[3]+=r0.w;
    o[4]+=r1.x; o[5]+=r1.y; o[6]+=r1.z; o[7]+=r1.w;
    o[8]+=r2.x; o[9]+=r2.y; o[10]+=r2.z; o[11]+=r2.w;
    o[12]+=r3.x; o[13]+=r3.y; o[14]+=r3.z; o[15]+=r3.w;
    l += pl[(size_t)(c * 4 + h) * N + n0 + lrow];
  }
  float inv = 1.0f / l;
#pragma unroll
  for (int r = 0; r < 16; ++r) {
    int d = (r & 3) + 8 * (r >> 2) + 4 * lhalf;   // C-layout row
    ao[lrow][h * 32 + d] = o[r] * inv;
  }
  __syncthreads();
  for (int i = tid; i < 32 * 32; i += 256) {
    int row = i >> 5, c4 = i & 31;
    *(float4*)(attno + (size_t)(n0 + row) * HID + c4 * 4) = *(float4*)&ao[row][c4 * 4];
  }
}

// ---------------------------------------------------------------- FFN fused (unchanged)
__global__ __launch_bounds__(256) void k_ffn(const float* __restrict__ fln,
    const float* __restrict__ w1, const float* __restrict__ b1,
    const float* __restrict__ w2, const float* __restrict__ b2,
    const float* __restrict__ eig, float* __restrict__ out) {
  __shared__ float fs[16][HID];
  __shared__ float t1[16][FF];
  int r0 = blockIdx.x * 16, tid = threadIdx.x;
  for (int i = tid; i < 16 * 32; i += 256) {
    int rr = i >> 5, c4 = i & 31;
    ((float4*)fs[rr])[c4] = *(const float4*)(fln + (size_t)(r0 + rr) * HID + c4 * 4);
  }
  __syncthreads();
  {
    float acc[16];
#pragma unroll
    for (int i = 0; i < 16; ++i) acc[i] = b1[tid];
    for (int k2 = 0; k2 < HID; ++k2) {
      float wv = w1[k2 * FF + tid];
#pragma unroll
      for (int i = 0; i < 16; ++i) acc[i] += fs[i][k2] * wv;
    }
#pragma unroll
    for (int i = 0; i < 16; ++i) {
      float xg = acc[i];
      t1[i][tid] = 0.5f * xg * (1.0f + erff(xg * 0.7071067811865476f));
    }
  }
  __syncthreads();
  int c = tid & 127, rb = tid >> 7;
  float acc2[8];
#pragma unroll
  for (int i = 0; i < 8; ++i) acc2[i] = b2[c];
  for (int k2 = 0; k2 < FF; ++k2) {
    float wv = w2[k2 * HID + c];
#pragma unroll
    for (int i = 0; i < 8; ++i) acc2[i] += t1[rb + 2 * i][k2] * wv;
  }
#pragma unroll
  for (int i = 0; i < 8; ++i) {
    int rr = r0 + rb + 2 * i;
    out[(size_t)rr * HID + c] = acc2[i] + eig[(size_t)rr * HID + c];
  }
}

// ---------------------------------------------------------------- decoder (unchanged)
__global__ __launch_bounds__(256) void k_dec(const float* __restrict__ eig2,
    const float* __restrict__ dw, const float* __restrict__ db, float* __restrict__ newe) {
  int idx = blockIdx.x * 256 + threadIdx.x;
  int n_ = idx >> 2, j = idx & 3;
  float a = db[j];
  for (int k2 = 0; k2 < HID; ++k2)
    a += eig2[(size_t)n_ * HID + k2] * dw[k2 * NHEAD + j];
  newe[idx] = a;
}

// ---------------------------------------------------------------- utx partials (unchanged)
__global__ __launch_bounds__(256) void k_utx(const float* __restrict__ u,
    const float* __restrict__ h, float* __restrict__ putx) {
  int m0 = blockIdx.x * 128;
  int nch = blockIdx.y;
  __shared__ float us[32][128];
  __shared__ float hs[32][NC];
  int tid = threadIdx.x;
  int m_l = tid & 127;
  int c0 = (tid >> 7) * 8;
  float acc[8];
#pragma unroll
  for (int j = 0; j < 8; ++j) acc[j] = 0.f;
  for (int n0 = nch * 512; n0 < nch * 512 + 512; n0 += 32) {
    __syncthreads();
    for (int i = tid; i < 32 * 32; i += 256) {
      int nl = i >> 5, c4 = i & 31;
      ((float4*)us[nl])[c4] = *(const float4*)(u + (size_t)(n0 + nl) * N + m0 + c4 * 4);
    }
    if (tid < 128) {
      int nl = tid >> 2, c4 = tid & 3;
      ((float4*)hs[nl])[c4] = *(const float4*)(h + (size_t)(n0 + nl) * NC + c4 * 4);
    }
    __syncthreads();
    for (int nl = 0; nl < 32; ++nl) {
      float uv = us[nl][m_l];
#pragma unroll
      for (int j = 0; j < 8; ++j) acc[j] += uv * hs[nl][c0 + j];
    }
  }
  float* o = putx + ((size_t)nch * N + m0 + m_l) * NC + c0;
#pragma unroll
  for (int j = 0; j < 8; ++j) o[j] = acc[j];
}

// ---------------------------------------------------------------- s build (unchanged)
__global__ __launch_bounds__(256) void k_sbuild(const float* __restrict__ putx,
    const float* __restrict__ newe, const float* __restrict__ specw,
    float* __restrict__ s) {
  int idx = blockIdx.x * 256 + threadIdx.x;
  int m = idx >> 4, c = idx & 15;
  float t = 0.f;
#pragma unroll
  for (int ch = 0; ch < 8; ++ch) t += putx[((size_t)ch * N + m) * NC + c];
  float fac = 0.f;
#pragma unroll
  for (int hh = 0; hh < NHEAD; ++hh) fac += newe[m * NHEAD + hh] * specw[(1 + hh) * NC + c];
  s[idx] = t * fac;
}

// ---------------------------------------------------------------- final (unchanged)
__global__ __launch_bounds__(256) void k_final(const float* __restrict__ u,
    const float* __restrict__ s, const float* __restrict__ h,
    const float* __restrict__ specw, float* __restrict__ out) {
  __shared__ float us[16][260];
  __shared__ float ssT[16][260];
  int n0 = blockIdx.x * 16, tid = threadIdx.x;
  int nl = tid >> 4, c = tid & 15;
  float a0 = 0, a1 = 0, a2 = 0, a3 = 0;
  for (int m0 = 0; m0 < N; m0 += 256) {
    __syncthreads();
    for (int i = tid; i < 16 * 64; i += 256) {
      int rr = i >> 6, c4 = i & 63;
      float4 t = *(const float4*)(u + (size_t)(n0 + rr) * N + m0 + c4 * 4);
      *(float4*)(&us[rr][c4 * 4]) = t;
    }
    for (int i = tid; i < 256 * 4; i += 256) {
      int mm = i >> 2, c4 = i & 3;
      float4 t = *(const float4*)(s + (size_t)(m0 + mm) * NC + c4 * 4);
      ssT[c4 * 4 + 0][mm] = t.x; ssT[c4 * 4 + 1][mm] = t.y;
      ssT[c4 * 4 + 2][mm] = t.z; ssT[c4 * 4 + 3][mm] = t.w;
    }
    __syncthreads();
#pragma unroll 8
    for (int mm = 0; mm < 256; mm += 4) {
      float4 uu = *(const float4*)(&us[nl][mm]);
      float4 s4 = *(const float4*)(&ssT[c][mm]);
      a0 += uu.x * s4.x; a1 += uu.y * s4.y; a2 += uu.z * s4.z; a3 += uu.w * s4.w;
    }
  }
  int n_ = n0 + nl;
  out[(size_t)n_ * NC + c] = (a0 + a1) + (a2 + a3) + h[(size_t)n_ * NC + c] * specw[c];
}

// ================================================================ launcher
extern "C" void kernel_launch(void* const* d_in, const int* in_sizes, int n_in,
                              void* d_out, int out_size, void* d_ws, size_t ws_size,
                              hipStream_t stream) {
  const float* e    = (const float*)d_in[0];
  const float* u    = (const float*)d_in[1];
  const float* x    = (const float*)d_in[2];
  const float* few1 = (const float*)d_in[3];
  const float* feb1 = (const float*)d_in[4];
  const float* few2 = (const float*)d_in[5];
  const float* feb2 = (const float*)d_in[6];
  const float* eww  = (const float*)d_in[7];
  const float* ewb  = (const float*)d_in[8];
  const float* ln1g = (const float*)d_in[9];
  const float* ln1b = (const float*)d_in[10];
  const float* wq   = (const float*)d_in[11];
  const float* bq   = (const float*)d_in[12];
  const float* wk   = (const float*)d_in[13];
  const float* bk   = (const float*)d_in[14];
  const float* wv_  = (const float*)d_in[15];
  const float* bv   = (const float*)d_in[16];
  const float* wo   = (const float*)d_in[17];
  const float* bo   = (const float*)d_in[18];
  const float* ln2g = (const float*)d_in[19];
  const float* ln2b = (const float*)d_in[20];
  const float* fw1  = (const float*)d_in[21];
  const float* fb1  = (const float*)d_in[22];
  const float* fw2  = (const float*)d_in[23];
  const float* fb2  = (const float*)d_in[24];
  const float* dw   = (const float*)d_in[25];
  const float* db   = (const float*)d_in[26];
  const float* spw  = (const float*)d_in[27];
  float* out = (float*)d_out;

  char* wsb = (char*)d_ws;
  auto alloc = [&](size_t bytes) { char* p = wsb; wsb += (bytes + 1023) & ~(size_t)1023; return p; };
  float* h    = (float*)alloc(N * NC * 4);
  f16*  sc_h  = (f16*)alloc(N * HID * 2);
  f16*  scS_h = (f16*)alloc(N * HID * 2);
  float* eigw = (float*)alloc(N * HID * 4);
  float* mln  = (float*)alloc(N * HID * 4);
  f16*  q_h   = (f16*)alloc(N * HID * 2);
  f16*  k_h   = (f16*)alloc(N * HID * 2);
  float* v    = (float*)alloc(N * HID * 4);
  f16*  vT_h  = (f16*)alloc(N * HID * 2);
  float* attno= (float*)alloc(N * HID * 4);
  float* eig  = (float*)alloc(N * HID * 4);
  float* fln  = (float*)alloc(N * HID * 4);
  float* eig2 = (float*)alloc(N * HID * 4);
  float* newe = (float*)alloc(N * NHEAD * 4);
  float* sarr = (float*)alloc(N * NC * 4);
  float* putx = (float*)alloc((size_t)8 * N * NC * 4);
  float* pacc = (float*)alloc((size_t)16 * 128 * 1024 * 4);
  float* pl   = (float*)alloc((size_t)16 * N * 4);
  size_t used = (size_t)(wsb - (char*)d_ws);
  size_t rel_f32_bytes = (size_t)128 * 128 * 1024 * 4;   // 67.1 MB
  size_t rel_f16_bytes = rel_f32_bytes / 2;
  bool R32 = (ws_size >= used + rel_f32_bytes + 4096);
  void* relf = (void*)alloc(R32 ? rel_f32_bytes : rel_f16_bytes);

  k_feat<<<N / 16, 256, 0, stream>>>(x, few1, feb1, few2, feb2, h);
  k_sine_eigw<<<N / 16, 256, 0, stream>>>(e, eww, ewb, sc_h, scS_h, eigw);
  k_ln<<<N / 4, 256, 0, stream>>>(eigw, ln1g, ln1b, mln);
  k_lin128<false, true><<<N / 16, 256, 0, stream>>>(mln, wq, bq, nullptr, nullptr, q_h, SCALE);
  k_lin128<false, true><<<N / 16, 256, 0, stream>>>(mln, wk, bk, nullptr, nullptr, k_h, 1.0f);
  k_lin128<false, false><<<N / 16, 256, 0, stream>>>(mln, wv_, bv, nullptr, v, nullptr, 1.0f);
  k_vT<<<N / 64, 256, 0, stream>>>(v, vT_h);
  if (R32) {
    k_relgemm<true><<<dim3(32, 32), 256, 0, stream>>>(scS_h, sc_h, relf);
    k_attn2<true><<<dim3(128, 4), 256, 0, stream>>>(q_h, k_h, vT_h, relf, pacc, pl);
  } else {
    k_relgemm<false><<<dim3(32, 32), 256, 0, stream>>>(scS_h, sc_h, relf);
    k_attn2<false><<<dim3(128, 4), 256, 0, stream>>>(q_h, k_h, vT_h, relf, pacc, pl);
  }
  k_attn_merge2<<<128, 256, 0, stream>>>(pacc, pl, attno);
  k_lin128<true, false><<<N / 16, 256, 0, stream>>>(attno, wo, bo, eigw, eig, nullptr, 1.0f);
  k_ln<<<N / 4, 256, 0, stream>>>(eig, ln2g, ln2b, fln);
  k_ffn<<<N / 16, 256, 0, stream>>>(fln, fw1, fb1, fw2, fb2, eig, eig2);
  k_dec<<<N * NHEAD / 256, 256, 0, stream>>>(eig2, dw, db, newe);
  k_utx<<<dim3(N / 128, 8), 256, 0, stream>>>(u, h, putx);
  k_sbuild<<<N * NC / 256, 256, 0, stream>>>(putx, newe, spw, sarr);
  k_final<<<N / 16, 256, 0, stream>>>(u, sarr, h, spw, out);
}

// Round 3
// 418.753 us; speedup vs baseline: 1.7592x; 1.2115x over previous
//
#include <hip/hip_runtime.h>
#include <math.h>

#define N 4096
#define NFEAT 512
#define HID 128
#define NHEAD 4
#define DH 32
#define NC 16
#define FF 256
#define NSPLIT 32     // k_utx n-split
#define NCHUNK 8      // attention m-chunks

typedef _Float16 f16;
typedef unsigned int uint;
typedef _Float16 f16x8 __attribute__((ext_vector_type(8)));
typedef _Float16 f16x2 __attribute__((ext_vector_type(2)));
typedef float f32x16 __attribute__((ext_vector_type(16)));

#define SCALE 0.17677669529663687f      // 1/sqrt(32)
#define LOG2E 1.44269504088896f
#define SH2   (-14.0f * 1.44269504088896f)   // fixed softmax shift (scores <= ~13.4)

// ---------------------------------------------------------------- K1: feat encoder (8 rows/block)
__global__ __launch_bounds__(256) void k_feat(const float* __restrict__ x,
    const float* __restrict__ w1, const float* __restrict__ b1,
    const float* __restrict__ w2, const float* __restrict__ b2,
    float* __restrict__ h) {
  __shared__ float xs[8][NFEAT];    // 16KB
  __shared__ float h1s[8][HID];     // 4KB
  int r0 = blockIdx.x * 8, tid = threadIdx.x;
  for (int i = tid; i < 8 * (NFEAT / 4); i += 256) {
    int rr = i >> 7, c4 = i & 127;
    ((float4*)xs[rr])[c4] = *(const float4*)(x + (size_t)(r0 + rr) * NFEAT + c4 * 4);
  }
  __syncthreads();
  int c = tid & 127, rb = tid >> 7;
  float acc[4];
#pragma unroll
  for (int i = 0; i < 4; ++i) acc[i] = b1[c];
  for (int k2 = 0; k2 < NFEAT; ++k2) {
    float wv = w1[k2 * HID + c];
#pragma unroll
    for (int i = 0; i < 4; ++i) acc[i] += xs[rb + 2 * i][k2] * wv;
  }
#pragma unroll
  for (int i = 0; i < 4; ++i) h1s[rb + 2 * i][c] = fmaxf(acc[i], 0.f);
  __syncthreads();
  if (tid < 128) {
    int rr = tid >> 4, cc = tid & 15;
    float a2 = b2[cc];
    for (int k2 = 0; k2 < HID; ++k2)
      a2 += h1s[rr][k2] * w2[k2 * NC + cc];
    h[(size_t)(r0 + rr) * NC + cc] = a2;
  }
}

// ---------------------------------------------------------------- K2: sine encoding + eig_w (8 rows/block)
__global__ __launch_bounds__(256) void k_sine_eigw(const float* __restrict__ e,
    const float* __restrict__ eww, const float* __restrict__ ewb,
    f16* __restrict__ sc_h, f16* __restrict__ scS_h, float* __restrict__ eigw) {
  __shared__ float scs[8][HID];
  __shared__ float es[8];
  int r0 = blockIdx.x * 8, tid = threadIdx.x;
  if (tid < 8) es[tid] = e[r0 + tid];
  __syncthreads();
  for (int i = tid; i < 8 * 64; i += 256) {
    int rr = i >> 6, j = i & 63;
    float div = expf((float)(2 * j) * (-0.07195578415606394f)); // -ln(10000)/128
    float pe = es[rr] * 100.0f * div;
    scs[rr][j]      = sinf(pe);
    scs[rr][j + 64] = cosf(pe);
  }
  __syncthreads();
  for (int i = tid; i < 8 * 64; i += 256) {
    int rr = i >> 6, jj = i & 63;
    float x0 = scs[rr][2 * jj], x1 = scs[rr][2 * jj + 1];
    f16x2 a; a[0] = (f16)x0; a[1] = (f16)x1;
    f16x2 b; b[0] = (f16)(x0 * SCALE); b[1] = (f16)(x1 * SCALE);
    ((f16x2*)sc_h)[(size_t)(r0 + rr) * 64 + jj] = a;
    ((f16x2*)scS_h)[(size_t)(r0 + rr) * 64 + jj] = b;
  }
  int c = tid & 127, rb = tid >> 7;
  float acc[4];
#pragma unroll
  for (int i = 0; i < 4; ++i) acc[i] = ewb[c] + es[rb + 2 * i] * eww[c];
  for (int k2 = 0; k2 < HID; ++k2) {
    float wv = eww[(1 + k2) * HID + c];
#pragma unroll
    for (int i = 0; i < 4; ++i) acc[i] += scs[rb + 2 * i][k2] * wv;
  }
#pragma unroll
  for (int i = 0; i < 4; ++i)
    eigw[(size_t)(r0 + rb + 2 * i) * HID + c] = acc[i];
}

// ---------------------------------------------------------------- LayerNorm (1 wave / row)
__global__ __launch_bounds__(256) void k_ln(const float* __restrict__ in,
    const float* __restrict__ g, const float* __restrict__ b, float* __restrict__ out) {
  int row = blockIdx.x * 4 + (threadIdx.x >> 6);
  int l = threadIdx.x & 63;
  float2 v2 = *(const float2*)(in + (size_t)row * HID + l * 2);
  float s = v2.x + v2.y;
  float ss = v2.x * v2.x + v2.y * v2.y;
#pragma unroll
  for (int off = 32; off > 0; off >>= 1) {
    s  += __shfl_down(s, off, 64);
    ss += __shfl_down(ss, off, 64);
  }
  s = __shfl(s, 0, 64); ss = __shfl(ss, 0, 64);
  float mean = s * (1.0f / HID);
  float var = ss * (1.0f / HID) - mean * mean;
  float inv = 1.0f / sqrtf(var + 1e-5f);
  float2 g2 = *(const float2*)(g + l * 2);
  float2 b2 = *(const float2*)(b + l * 2);
  float2 o;
  o.x = (v2.x - mean) * inv * g2.x + b2.x;
  o.y = (v2.y - mean) * inv * g2.y + b2.y;
  *(float2*)(out + (size_t)row * HID + l * 2) = o;
}

// ---------------------------------------------------------------- [*,128]@[128,128] (8 rows/block)
template <bool RES, bool F16O>
__global__ __launch_bounds__(256) void k_lin128(const float* __restrict__ in,
    const float* __restrict__ w, const float* __restrict__ bias,
    const float* __restrict__ res, float* __restrict__ out, f16* __restrict__ outh,
    float oscale) {
  __shared__ float as[8][HID];
  int r0 = blockIdx.x * 8, tid = threadIdx.x;
  {
    int rr = tid >> 5, c4 = tid & 31;
    ((float4*)as[rr])[c4] = *(const float4*)(in + (size_t)(r0 + rr) * HID + c4 * 4);
  }
  __syncthreads();
  int c = tid & 127, rb = tid >> 7;
  float acc[4];
#pragma unroll
  for (int i = 0; i < 4; ++i) acc[i] = bias[c];
  for (int k2 = 0; k2 < HID; ++k2) {
    float wv = w[k2 * HID + c];
#pragma unroll
    for (int i = 0; i < 4; ++i) acc[i] += as[rb + 2 * i][k2] * wv;
  }
#pragma unroll
  for (int i = 0; i < 4; ++i) {
    int rr = rb + 2 * i;
    float o = acc[i];
    if (RES) o += res[(size_t)(r0 + rr) * HID + c];
    if (F16O) outh[(size_t)(r0 + rr) * HID + c] = (f16)(o * oscale);
    else      out[(size_t)(r0 + rr) * HID + c] = o;
  }
}

// ---------------------------------------------------------------- v (f32) -> vT (f16, [128][N]); LDS-free
__global__ __launch_bounds__(256) void k_vT(const float* __restrict__ v, f16* __restrict__ vT) {
  int n0 = blockIdx.x * 64, d0 = blockIdx.y * 32, tid = threadIdx.x;
  int d = tid & 31;
#pragma unroll
  for (int it = 0; it < 4; ++it) {
    int j = (tid >> 5) + it * 8;                 // n-pair within 64-row tile
    float x0 = v[(size_t)(n0 + 2 * j) * HID + d0 + d];
    float x1 = v[(size_t)(n0 + 2 * j + 1) * HID + d0 + d];
    f16x2 hh; hh[0] = (f16)x0; hh[1] = (f16)x1;
    ((f16x2*)vT)[((size_t)(d0 + d) * N + n0) / 2 + j] = hh;
  }
}

// ---------------------------------------------------------------- fused MFMA flash attention + on-the-fly rel
// 4 waves = 4 heads, n-tile 32, m-chunk 512. S^T = scS@sc^T (8 mfma) + mfma(K,Q); fixed-shift softmax;
// P -> f16 B-frags in-register; O^T += mfma(vT, P). Zero LDS; K/V/sc/scS all L2-hot.
__global__ __launch_bounds__(256) void k_attn2(const f16* __restrict__ qh, const f16* __restrict__ kh,
    const f16* __restrict__ vTh, const f16* __restrict__ sch, const f16* __restrict__ scSh,
    float* __restrict__ pacc, float* __restrict__ pl) {
  int tid = threadIdx.x, h = tid >> 6, lane = tid & 63, lrow = lane & 31, lhalf = lane >> 5;
  int n0 = blockIdx.x * 32, ntile = blockIdx.x, chunk = blockIdx.y;
  const f16* qp = qh + (size_t)(n0 + lrow) * HID + 32 * h + lhalf * 8;
  f16x8 qb0 = *(const f16x8*)(qp);
  f16x8 qb1 = *(const f16x8*)(qp + 16);
  f16x8 bsc[8];   // hoisted rel B-frags (sc rows n0..n0+31)
#pragma unroll
  for (int ks = 0; ks < 8; ++ks)
    bsc[ks] = *(const f16x8*)(sch + (size_t)(n0 + lrow) * HID + ks * 16 + lhalf * 8);
  f32x16 oacc = {0,0,0,0,0,0,0,0,0,0,0,0,0,0,0,0};
  float l = 0.f;
  for (int mt = 0; mt < 16; ++mt) {
    int m0 = chunk * 512 + mt * 32;
    const f16* kp = kh + (size_t)(m0 + lrow) * HID + 32 * h + lhalf * 8;
    f16x8 ka0 = *(const f16x8*)(kp);
    f16x8 ka1 = *(const f16x8*)(kp + 16);
    const f16* vp = vTh + (size_t)(32 * h + lrow) * N + m0 + lhalf * 8;
    f16x8 va0 = *(const f16x8*)(vp);
    f16x8 va1 = *(const f16x8*)(vp + 16);
    f32x16 sacc = {0,0,0,0,0,0,0,0,0,0,0,0,0,0,0,0};
#pragma unroll
    for (int ks = 0; ks < 8; ++ks) {
      f16x8 as = *(const f16x8*)(scSh + (size_t)(m0 + lrow) * HID + ks * 16 + lhalf * 8);
      sacc = __builtin_amdgcn_mfma_f32_32x32x16_f16(as, bsc[ks], sacc, 0, 0, 0);
    }
    sacc = __builtin_amdgcn_mfma_f32_32x32x16_f16(ka0, qb0, sacc, 0, 0, 0);
    sacc = __builtin_amdgcn_mfma_f32_32x32x16_f16(ka1, qb1, sacc, 0, 0, 0);
    // fixed-shift softmax + in-register P->B-frag packing
    uint w0[2], w1[2], w2[2], w3[2];
#pragma unroll
    for (int ks = 0; ks < 2; ++ks) {
      float p[8];
#pragma unroll
      for (int i = 0; i < 8; ++i)
        p[i] = exp2f(fmaf(sacc[ks * 8 + i], LOG2E, SH2));
      uint Wa = __builtin_bit_cast(uint, __builtin_amdgcn_cvt_pkrtz(p[0], p[1]));
      uint Wb = __builtin_bit_cast(uint, __builtin_amdgcn_cvt_pkrtz(p[2], p[3]));
      uint Wc = __builtin_bit_cast(uint, __builtin_amdgcn_cvt_pkrtz(p[4], p[5]));
      uint Wd = __builtin_bit_cast(uint, __builtin_amdgcn_cvt_pkrtz(p[6], p[7]));
      {
        f16x2 ha = __builtin_bit_cast(f16x2, Wa), hb = __builtin_bit_cast(f16x2, Wb);
        f16x2 hc = __builtin_bit_cast(f16x2, Wc), hd = __builtin_bit_cast(f16x2, Wd);
        l += (float)ha[0] + (float)ha[1] + (float)hb[0] + (float)hb[1]
           + (float)hc[0] + (float)hc[1] + (float)hd[0] + (float)hd[1];
      }
      uint Wax = (uint)__shfl_xor((int)Wa, 32, 64);
      uint Wbx = (uint)__shfl_xor((int)Wb, 32, 64);
      uint Wcx = (uint)__shfl_xor((int)Wc, 32, 64);
      uint Wdx = (uint)__shfl_xor((int)Wd, 32, 64);
      bool hi = (lhalf != 0);
      w0[ks] = hi ? Wcx : Wa;
      w1[ks] = hi ? Wdx : Wb;
      w2[ks] = hi ? Wc : Wax;
      w3[ks] = hi ? Wd : Wbx;
    }
    f16x8 pb0 = __builtin_bit_cast(f16x8, make_uint4(w0[0], w1[0], w2[0], w3[0]));
    f16x8 pb1 = __builtin_bit_cast(f16x8, make_uint4(w0[1], w1[1], w2[1], w3[1]));
    oacc = __builtin_amdgcn_mfma_f32_32x32x16_f16(va0, pb0, oacc, 0, 0, 0);
    oacc = __builtin_amdgcn_mfma_f32_32x32x16_f16(va1, pb1, oacc, 0, 0, 0);
  }
  l += __shfl_xor(l, 32, 64);
  float* pp = pacc + ((size_t)(chunk * 4 + h) * 128 + ntile) * 1024 + lane * 16;
  *(float4*)(pp +  0) = make_float4(oacc[0],  oacc[1],  oacc[2],  oacc[3]);
  *(float4*)(pp +  4) = make_float4(oacc[4],  oacc[5],  oacc[6],  oacc[7]);
  *(float4*)(pp +  8) = make_float4(oacc[8],  oacc[9],  oacc[10], oacc[11]);
  *(float4*)(pp + 12) = make_float4(oacc[12], oacc[13], oacc[14], oacc[15]);
  if (lane < 32) pl[(size_t)(chunk * 4 + h) * N + n0 + lrow] = l;
}

// ---------------------------------------------------------------- merge 8 m-chunks (fixed shift -> plain sums)
__global__ __launch_bounds__(256) void k_attn_merge2(const float* __restrict__ pacc,
    const float* __restrict__ pl, float* __restrict__ attno) {
  __shared__ float ao[32][132];
  int tid = threadIdx.x, h = tid >> 6, lane = tid & 63, lrow = lane & 31, lhalf = lane >> 5;
  int ntile = blockIdx.x, n0 = ntile * 32;
  float o[16];
#pragma unroll
  for (int r = 0; r < 16; ++r) o[r] = 0.f;
  float l = 0.f;
#pragma unroll
  for (int c = 0; c < NCHUNK; ++c) {
    const float* pp = pacc + ((size_t)(c * 4 + h) * 128 + ntile) * 1024 + lane * 16;
    float4 r0 = *(const float4*)(pp), r1 = *(const float4*)(pp + 4);
    float4 r2 = *(const float4*)(pp + 8), r3 = *(const float4*)(pp + 12);
    o[0]+=r0.x; o[1]+=r0.y; o[2]+=r0.z; o[3]+=r0.w;
    o[4]+=r1.x; o[5]+=r1.y; o[6]+=r1.z; o[7]+=r1.w;
    o[8]+=r2.x; o[9]+=r2.y; o[10]+=r2.z; o[11]+=r2.w;
    o[12]+=r3.x; o[13]+=r3.y; o[14]+=r3.z; o[15]+=r3.w;
    l += pl[(size_t)(c * 4 + h) * N + n0 + lrow];
  }
  float inv = 1.0f / l;
#pragma unroll
  for (int r = 0; r < 16; ++r) {
    int d = (r & 3) + 8 * (r >> 2) + 4 * lhalf;   // C-layout row
    ao[lrow][h * 32 + d] = o[r] * inv;
  }
  __syncthreads();
  for (int i = tid; i < 32 * 32; i += 256) {
    int row = i >> 5, c4 = i & 31;
    *(float4*)(attno + (size_t)(n0 + row) * HID + c4 * 4) = *(float4*)&ao[row][c4 * 4];
  }
}

// ---------------------------------------------------------------- FFN fused (8 rows/block)
__global__ __launch_bounds__(256) void k_ffn(const float* __restrict__ fln,
    const float* __restrict__ w1, const float* __restrict__ b1,
    const float* __restrict__ w2, const float* __restrict__ b2,
    const float* __restrict__ eig, float* __restrict__ out) {
  __shared__ float fs[8][HID];
  __shared__ float t1[8][FF];
  int r0 = blockIdx.x * 8, tid = threadIdx.x;
  {
    int rr = tid >> 5, c4 = tid & 31;
    ((float4*)fs[rr])[c4] = *(const float4*)(fln + (size_t)(r0 + rr) * HID + c4 * 4);
  }
  __syncthreads();
  {
    float acc[8];
#pragma unroll
    for (int i = 0; i < 8; ++i) acc[i] = b1[tid];
    for (int k2 = 0; k2 < HID; ++k2) {
      float wv = w1[k2 * FF + tid];
#pragma unroll
      for (int i = 0; i < 8; ++i) acc[i] += fs[i][k2] * wv;
    }
#pragma unroll
    for (int i = 0; i < 8; ++i) {
      float xg = acc[i];
      t1[i][tid] = 0.5f * xg * (1.0f + erff(xg * 0.7071067811865476f));
    }
  }
  __syncthreads();
  int c = tid & 127, rb = tid >> 7;
  float acc2[4];
#pragma unroll
  for (int i = 0; i < 4; ++i) acc2[i] = b2[c];
  for (int k2 = 0; k2 < FF; ++k2) {
    float wv = w2[k2 * HID + c];
#pragma unroll
    for (int i = 0; i < 4; ++i) acc2[i] += t1[rb + 2 * i][k2] * wv;
  }
#pragma unroll
  for (int i = 0; i < 4; ++i) {
    int rr = r0 + rb + 2 * i;
    out[(size_t)rr * HID + c] = acc2[i] + eig[(size_t)rr * HID + c];
  }
}

// ---------------------------------------------------------------- decoder (16 rows/block, split-k)
__global__ __launch_bounds__(256) void k_dec(const float* __restrict__ eig2,
    const float* __restrict__ dw, const float* __restrict__ db, float* __restrict__ newe) {
  int tid = threadIdx.x;
  int r = tid >> 4, j = (tid >> 2) & 3, q = tid & 3;
  int n = blockIdx.x * 16 + r;
  const float* ep = eig2 + (size_t)n * HID + q * 32;
  float a = 0.f;
#pragma unroll
  for (int t4 = 0; t4 < 8; ++t4) {
    float4 e4 = *(const float4*)(ep + t4 * 4);
    int k0 = q * 32 + t4 * 4;
    a += e4.x * dw[k0 * NHEAD + j] + e4.y * dw[(k0 + 1) * NHEAD + j]
       + e4.z * dw[(k0 + 2) * NHEAD + j] + e4.w * dw[(k0 + 3) * NHEAD + j];
  }
  a += __shfl_down(a, 1, 64);
  a += __shfl_down(a, 2, 64);
  if (q == 0) newe[n * NHEAD + j] = db[j] + a;
}

// ---------------------------------------------------------------- utx partials: u^T @ h, n-split 32
__global__ __launch_bounds__(256) void k_utx(const float* __restrict__ u,
    const float* __restrict__ h, float* __restrict__ putx) {
  __shared__ float hs[128][NC];   // 8KB
  int tid = threadIdx.x;
  int m = blockIdx.x * 256 + tid;
  int n0 = blockIdx.y * 128;
  for (int i = tid; i < 128 * 4; i += 256) {
    int row = i >> 2, cq = i & 3;
    ((float4*)hs[row])[cq] = *(const float4*)(h + (size_t)(n0 + row) * NC + cq * 4);
  }
  __syncthreads();
  float acc[16];
#pragma unroll
  for (int c = 0; c < 16; ++c) acc[c] = 0.f;
  for (int nb = 0; nb < 16; ++nb) {
    float uv[8];
#pragma unroll
    for (int t = 0; t < 8; ++t)
      uv[t] = u[(size_t)(n0 + nb * 8 + t) * N + m];
#pragma unroll
    for (int t = 0; t < 8; ++t) {
      int nl = nb * 8 + t;
      float4 h0 = ((const float4*)hs[nl])[0];
      float4 h1 = ((const float4*)hs[nl])[1];
      float4 h2 = ((const float4*)hs[nl])[2];
      float4 h3 = ((const float4*)hs[nl])[3];
      acc[0]  += uv[t] * h0.x;  acc[1]  += uv[t] * h0.y;
      acc[2]  += uv[t] * h0.z;  acc[3]  += uv[t] * h0.w;
      acc[4]  += uv[t] * h1.x;  acc[5]  += uv[t] * h1.y;
      acc[6]  += uv[t] * h1.z;  acc[7]  += uv[t] * h1.w;
      acc[8]  += uv[t] * h2.x;  acc[9]  += uv[t] * h2.y;
      acc[10] += uv[t] * h2.z;  acc[11] += uv[t] * h2.w;
      acc[12] += uv[t] * h3.x;  acc[13] += uv[t] * h3.y;
      acc[14] += uv[t] * h3.z;  acc[15] += uv[t] * h3.w;
    }
  }
  float* o = putx + ((size_t)blockIdx.y * N + m) * NC;
  *(float4*)(o +  0) = make_float4(acc[0],  acc[1],  acc[2],  acc[3]);
  *(float4*)(o +  4) = make_float4(acc[4],  acc[5],  acc[6],  acc[7]);
  *(float4*)(o +  8) = make_float4(acc[8],  acc[9],  acc[10], acc[11]);
  *(float4*)(o + 12) = make_float4(acc[12], acc[13], acc[14], acc[15]);
}

// ---------------------------------------------------------------- s build: sum partials, scale, output TRANSPOSED sT[16][N]
__global__ __launch_bounds__(256) void k_sbuild(const float* __restrict__ putx,
    const float* __restrict__ newe, const float* __restrict__ specw,
    float* __restrict__ sT) {
  int i = blockIdx.x * 256 + threadIdx.x;   // (m, cq)
  int m = i >> 2, cq = i & 3;
  float4 t = make_float4(0.f, 0.f, 0.f, 0.f);
#pragma unroll 8
  for (int ch = 0; ch < NSPLIT; ++ch) {
    float4 p = *(const float4*)(putx + ((size_t)ch * N + m) * NC + cq * 4);
    t.x += p.x; t.y += p.y; t.z += p.z; t.w += p.w;
  }
  float4 ne = *(const float4*)(newe + (size_t)m * NHEAD);
  float fac[4];
#pragma unroll
  for (int cc = 0; cc < 4; ++cc) {
    int c = cq * 4 + cc;
    fac[cc] = ne.x * specw[1 * NC + c] + ne.y * specw[2 * NC + c]
            + ne.z * specw[3 * NC + c] + ne.w * specw[4 * NC + c];
  }
  sT[(size_t)(cq * 4 + 0) * N + m] = t.x * fac[0];
  sT[(size_t)(cq * 4 + 1) * N + m] = t.y * fac[1];
  sT[(size_t)(cq * 4 + 2) * N + m] = t.z * fac[2];
  sT[(size_t)(cq * 4 + 3) * N + m] = t.w * fac[3];
}

// ---------------------------------------------------------------- u @ s partials: 16 rows/block, m-split 2
__global__ __launch_bounds__(256) void k_final(const float* __restrict__ u,
    const float* __restrict__ sT, float* __restrict__ pfin) {
  __shared__ float sTl[16][256];   // 16KB
  int tid = threadIdx.x, w = tid >> 6, lane = tid & 63;
  int r0 = blockIdx.x * 16;
  size_t mbase = (size_t)blockIdx.y * 2048;
  float a[4][16];
#pragma unroll
  for (int r = 0; r < 4; ++r)
#pragma unroll
    for (int c = 0; c < 16; ++c) a[r][c] = 0.f;
  for (int chunk = 0; chunk < 8; ++chunk) {
    size_t mc0 = mbase + chunk * 256;
    __syncthreads();
    for (int i = tid; i < 16 * 64; i += 256) {
      int c = i >> 6, q = i & 63;
      ((float4*)&sTl[c][0])[q] = *(const float4*)(sT + (size_t)c * N + mc0 + q * 4);
    }
    __syncthreads();
    float4 u4[4];
#pragma unroll
    for (int r = 0; r < 4; ++r)
      u4[r] = *(const float4*)(u + (size_t)(r0 + w * 4 + r) * N + mc0 + 4 * lane);
#pragma unroll
    for (int c = 0; c < 16; ++c) {
      float4 sv = *(const float4*)&sTl[c][4 * lane];
#pragma unroll
      for (int r = 0; r < 4; ++r)
        a[r][c] += u4[r].x * sv.x + u4[r].y * sv.y + u4[r].z * sv.z + u4[r].w * sv.w;
    }
  }
#pragma unroll
  for (int off = 32; off > 0; off >>= 1)
#pragma unroll
    for (int r = 0; r < 4; ++r)
#pragma unroll
      for (int c = 0; c < 16; ++c)
        a[r][c] += __shfl_xor(a[r][c], off, 64);
  if (lane == 0) {
#pragma unroll
    for (int r = 0; r < 4; ++r) {
      float* op = pfin + ((size_t)blockIdx.y * N + r0 + w * 4 + r) * NC;
      *(float4*)(op +  0) = make_float4(a[r][0],  a[r][1],  a[r][2],  a[r][3]);
      *(float4*)(op +  4) = make_float4(a[r][4],  a[r][5],  a[r][6],  a[r][7]);
      *(float4*)(op +  8) = make_float4(a[r][8],  a[r][9],  a[r][10], a[r][11]);
      *(float4*)(op + 12) = make_float4(a[r][12], a[r][13], a[r][14], a[r][15]);
    }
  }
}

// ---------------------------------------------------------------- final merge: pfin halves + h*specw0
__global__ __launch_bounds__(256) void k_finmerge(const float* __restrict__ pfin,
    const float* __restrict__ h, const float* __restrict__ specw, float* __restrict__ out) {
  int i = blockIdx.x * 256 + threadIdx.x;   // quad id
  int n = i >> 2, cq = i & 3;
  float4 f0 = *(const float4*)(pfin + (size_t)n * NC + cq * 4);
  float4 f1 = *(const float4*)(pfin + ((size_t)N + n) * NC + cq * 4);
  float4 h4 = *(const float4*)(h + (size_t)n * NC + cq * 4);
  int c0 = cq * 4;
  float4 o;
  o.x = f0.x + f1.x + h4.x * specw[c0 + 0];
  o.y = f0.y + f1.y + h4.y * specw[c0 + 1];
  o.z = f0.z + f1.z + h4.z * specw[c0 + 2];
  o.w = f0.w + f1.w + h4.w * specw[c0 + 3];
  *(float4*)(out + (size_t)n * NC + cq * 4) = o;
}

// ================================================================ launcher
extern "C" void kernel_launch(void* const* d_in, const int* in_sizes, int n_in,
                              void* d_out, int out_size, void* d_ws, size_t ws_size,
                              hipStream_t stream) {
  const float* e    = (const float*)d_in[0];
  const float* u    = (const float*)d_in[1];
  const float* x    = (const float*)d_in[2];
  const float* few1 = (const float*)d_in[3];
  const float* feb1 = (const float*)d_in[4];
  const float* few2 = (const float*)d_in[5];
  const float* feb2 = (const float*)d_in[6];
  const float* eww  = (const float*)d_in[7];
  const float* ewb  = (const float*)d_in[8];
  const float* ln1g = (const float*)d_in[9];
  const float* ln1b = (const float*)d_in[10];
  const float* wq   = (const float*)d_in[11];
  const float* bq   = (const float*)d_in[12];
  const float* wk   = (const float*)d_in[13];
  const float* bk   = (const float*)d_in[14];
  const float* wv_  = (const float*)d_in[15];
  const float* bv   = (const float*)d_in[16];
  const float* wo   = (const float*)d_in[17];
  const float* bo   = (const float*)d_in[18];
  const float* ln2g = (const float*)d_in[19];
  const float* ln2b = (const float*)d_in[20];
  const float* fw1  = (const float*)d_in[21];
  const float* fb1  = (const float*)d_in[22];
  const float* fw2  = (const float*)d_in[23];
  const float* fb2  = (const float*)d_in[24];
  const float* dw   = (const float*)d_in[25];
  const float* db   = (const float*)d_in[26];
  const float* spw  = (const float*)d_in[27];
  float* out = (float*)d_out;

  char* wsb = (char*)d_ws;
  auto alloc = [&](size_t bytes) { char* p = wsb; wsb += (bytes + 1023) & ~(size_t)1023; return p; };
  float* h    = (float*)alloc(N * NC * 4);
  f16*  sc_h  = (f16*)alloc(N * HID * 2);
  f16*  scS_h = (f16*)alloc(N * HID * 2);
  float* eigw = (float*)alloc(N * HID * 4);
  float* mln  = (float*)alloc(N * HID * 4);
  f16*  q_h   = (f16*)alloc(N * HID * 2);
  f16*  k_h   = (f16*)alloc(N * HID * 2);
  float* v    = (float*)alloc(N * HID * 4);
  f16*  vT_h  = (f16*)alloc(N * HID * 2);
  float* attno= (float*)alloc(N * HID * 4);
  float* eig  = (float*)alloc(N * HID * 4);
  float* fln  = (float*)alloc(N * HID * 4);
  float* eig2 = (float*)alloc(N * HID * 4);
  float* newe = (float*)alloc(N * NHEAD * 4);
  float* sT   = (float*)alloc((size_t)NC * N * 4);
  float* putx = (float*)alloc((size_t)NSPLIT * N * NC * 4);
  float* pacc = (float*)alloc((size_t)NCHUNK * 4 * 128 * 1024 * 4);
  float* pl   = (float*)alloc((size_t)NCHUNK * 4 * N * 4);
  float* pfin = (float*)alloc((size_t)2 * N * NC * 4);

  k_feat<<<N / 8, 256, 0, stream>>>(x, few1, feb1, few2, feb2, h);
  k_utx<<<dim3(N / 256, NSPLIT), 256, 0, stream>>>(u, h, putx);
  k_sine_eigw<<<N / 8, 256, 0, stream>>>(e, eww, ewb, sc_h, scS_h, eigw);
  k_ln<<<N / 4, 256, 0, stream>>>(eigw, ln1g, ln1b, mln);
  k_lin128<false, true><<<N / 8, 256, 0, stream>>>(mln, wq, bq, nullptr, nullptr, q_h, SCALE);
  k_lin128<false, true><<<N / 8, 256, 0, stream>>>(mln, wk, bk, nullptr, nullptr, k_h, 1.0f);
  k_lin128<false, false><<<N / 8, 256, 0, stream>>>(mln, wv_, bv, nullptr, v, nullptr, 1.0f);
  k_vT<<<dim3(N / 64, 4), 256, 0, stream>>>(v, vT_h);
  k_attn2<<<dim3(128, NCHUNK), 256, 0, stream>>>(q_h, k_h, vT_h, sc_h, scS_h, pacc, pl);
  k_attn_merge2<<<128, 256, 0, stream>>>(pacc, pl, attno);
  k_lin128<true, false><<<N / 8, 256, 0, stream>>>(attno, wo, bo, eigw, eig, nullptr, 1.0f);
  k_ln<<<N / 4, 256, 0, stream>>>(eig, ln2g, ln2b, fln);
  k_ffn<<<N / 8, 256, 0, stream>>>(fln, fw1, fb1, fw2, fb2, eig, eig2);
  k_dec<<<N / 16, 256, 0, stream>>>(eig2, dw, db, newe);
  k_sbuild<<<N * 4 / 256, 256, 0, stream>>>(putx, newe, spw, sT);
  k_final<<<dim3(N / 16, 2), 256, 0, stream>>>(u, sT, pfin);
  k_finmerge<<<N * 4 / 256, 256, 0, stream>>>(pfin, h, spw, out);
}

// Round 4
// 377.990 us; speedup vs baseline: 1.9490x; 1.1078x over previous
//
#include <hip/hip_runtime.h>
#include <math.h>

#define N 4096
#define NFEAT 512
#define HID 128
#define NHEAD 4
#define DH 32
#define NC 16
#define FF 256
#define NSPLIT 32     // k_utx n-split
#define NCHUNK 8      // attention m-chunks
#define CHUNKM (N / NCHUNK)   // 512
#define NGRP (CHUNKM / 128)   // 4 groups of 4 m-tiles

typedef _Float16 f16;
typedef unsigned int uint;
typedef _Float16 f16x8 __attribute__((ext_vector_type(8)));
typedef _Float16 f16x2 __attribute__((ext_vector_type(2)));
typedef float f32x16 __attribute__((ext_vector_type(16)));

#define SCALE 0.17677669529663687f      // 1/sqrt(32)
#define LOG2E 1.44269504088896f
#define SH2   (-14.0f * 1.44269504088896f)   // fixed softmax shift (scores <= ~13.4)

// ---------------------------------------------------------------- K1: feat encoder (8 rows/block)
__global__ __launch_bounds__(256) void k_feat(const float* __restrict__ x,
    const float* __restrict__ w1, const float* __restrict__ b1,
    const float* __restrict__ w2, const float* __restrict__ b2,
    float* __restrict__ h) {
  __shared__ float xs[8][NFEAT];    // 16KB
  __shared__ float h1s[8][HID];     // 4KB
  int r0 = blockIdx.x * 8, tid = threadIdx.x;
  for (int i = tid; i < 8 * (NFEAT / 4); i += 256) {
    int rr = i >> 7, c4 = i & 127;
    ((float4*)xs[rr])[c4] = *(const float4*)(x + (size_t)(r0 + rr) * NFEAT + c4 * 4);
  }
  __syncthreads();
  int c = tid & 127, rb = tid >> 7;
  float acc[4];
#pragma unroll
  for (int i = 0; i < 4; ++i) acc[i] = b1[c];
  for (int k2 = 0; k2 < NFEAT; ++k2) {
    float wv = w1[k2 * HID + c];
#pragma unroll
    for (int i = 0; i < 4; ++i) acc[i] += xs[rb + 2 * i][k2] * wv;
  }
#pragma unroll
  for (int i = 0; i < 4; ++i) h1s[rb + 2 * i][c] = fmaxf(acc[i], 0.f);
  __syncthreads();
  if (tid < 128) {
    int rr = tid >> 4, cc = tid & 15;
    float a2 = b2[cc];
    for (int k2 = 0; k2 < HID; ++k2)
      a2 += h1s[rr][k2] * w2[k2 * NC + cc];
    h[(size_t)(r0 + rr) * NC + cc] = a2;
  }
}

// ---------------------------------------------------------------- K2: sine encoding + eig_w (8 rows/block)
__global__ __launch_bounds__(256) void k_sine_eigw(const float* __restrict__ e,
    const float* __restrict__ eww, const float* __restrict__ ewb,
    f16* __restrict__ sc_h, f16* __restrict__ scS_h, float* __restrict__ eigw) {
  __shared__ float scs[8][HID];
  __shared__ float es[8];
  int r0 = blockIdx.x * 8, tid = threadIdx.x;
  if (tid < 8) es[tid] = e[r0 + tid];
  __syncthreads();
  for (int i = tid; i < 8 * 64; i += 256) {
    int rr = i >> 6, j = i & 63;
    float div = expf((float)(2 * j) * (-0.07195578415606394f)); // -ln(10000)/128
    float pe = es[rr] * 100.0f * div;
    scs[rr][j]      = sinf(pe);
    scs[rr][j + 64] = cosf(pe);
  }
  __syncthreads();
  for (int i = tid; i < 8 * 64; i += 256) {
    int rr = i >> 6, jj = i & 63;
    float x0 = scs[rr][2 * jj], x1 = scs[rr][2 * jj + 1];
    f16x2 a; a[0] = (f16)x0; a[1] = (f16)x1;
    f16x2 b; b[0] = (f16)(x0 * SCALE); b[1] = (f16)(x1 * SCALE);
    ((f16x2*)sc_h)[(size_t)(r0 + rr) * 64 + jj] = a;
    ((f16x2*)scS_h)[(size_t)(r0 + rr) * 64 + jj] = b;
  }
  int c = tid & 127, rb = tid >> 7;
  float acc[4];
#pragma unroll
  for (int i = 0; i < 4; ++i) acc[i] = ewb[c] + es[rb + 2 * i] * eww[c];
  for (int k2 = 0; k2 < HID; ++k2) {
    float wv = eww[(1 + k2) * HID + c];
#pragma unroll
    for (int i = 0; i < 4; ++i) acc[i] += scs[rb + 2 * i][k2] * wv;
  }
#pragma unroll
  for (int i = 0; i < 4; ++i)
    eigw[(size_t)(r0 + rb + 2 * i) * HID + c] = acc[i];
}

// ---------------------------------------------------------------- LayerNorm (1 wave / row)
__global__ __launch_bounds__(256) void k_ln(const float* __restrict__ in,
    const float* __restrict__ g, const float* __restrict__ b, float* __restrict__ out) {
  int row = blockIdx.x * 4 + (threadIdx.x >> 6);
  int l = threadIdx.x & 63;
  float2 v2 = *(const float2*)(in + (size_t)row * HID + l * 2);
  float s = v2.x + v2.y;
  float ss = v2.x * v2.x + v2.y * v2.y;
#pragma unroll
  for (int off = 32; off > 0; off >>= 1) {
    s  += __shfl_down(s, off, 64);
    ss += __shfl_down(ss, off, 64);
  }
  s = __shfl(s, 0, 64); ss = __shfl(ss, 0, 64);
  float mean = s * (1.0f / HID);
  float var = ss * (1.0f / HID) - mean * mean;
  float inv = 1.0f / sqrtf(var + 1e-5f);
  float2 g2 = *(const float2*)(g + l * 2);
  float2 b2 = *(const float2*)(b + l * 2);
  float2 o;
  o.x = (v2.x - mean) * inv * g2.x + b2.x;
  o.y = (v2.y - mean) * inv * g2.y + b2.y;
  *(float2*)(out + (size_t)row * HID + l * 2) = o;
}

// ---------------------------------------------------------------- [*,128]@[128,128] (8 rows/block)
template <bool RES, bool F16O>
__global__ __launch_bounds__(256) void k_lin128(const float* __restrict__ in,
    const float* __restrict__ w, const float* __restrict__ bias,
    const float* __restrict__ res, float* __restrict__ out, f16* __restrict__ outh,
    float oscale) {
  __shared__ float as[8][HID];
  int r0 = blockIdx.x * 8, tid = threadIdx.x;
  {
    int rr = tid >> 5, c4 = tid & 31;
    ((float4*)as[rr])[c4] = *(const float4*)(in + (size_t)(r0 + rr) * HID + c4 * 4);
  }
  __syncthreads();
  int c = tid & 127, rb = tid >> 7;
  float acc[4];
#pragma unroll
  for (int i = 0; i < 4; ++i) acc[i] = bias[c];
  for (int k2 = 0; k2 < HID; ++k2) {
    float wv = w[k2 * HID + c];
#pragma unroll
    for (int i = 0; i < 4; ++i) acc[i] += as[rb + 2 * i][k2] * wv;
  }
#pragma unroll
  for (int i = 0; i < 4; ++i) {
    int rr = rb + 2 * i;
    float o = acc[i];
    if (RES) o += res[(size_t)(r0 + rr) * HID + c];
    if (F16O) outh[(size_t)(r0 + rr) * HID + c] = (f16)(o * oscale);
    else      out[(size_t)(r0 + rr) * HID + c] = o;
  }
}

// ---------------------------------------------------------------- v (f32) -> vT (f16, [128][N]); LDS-free
__global__ __launch_bounds__(256) void k_vT(const float* __restrict__ v, f16* __restrict__ vT) {
  int n0 = blockIdx.x * 64, d0 = blockIdx.y * 32, tid = threadIdx.x;
  int d = tid & 31;
#pragma unroll
  for (int it = 0; it < 4; ++it) {
    int j = (tid >> 5) + it * 8;                 // n-pair within 64-row tile
    float x0 = v[(size_t)(n0 + 2 * j) * HID + d0 + d];
    float x1 = v[(size_t)(n0 + 2 * j + 1) * HID + d0 + d];
    f16x2 hh; hh[0] = (f16)x0; hh[1] = (f16)x1;
    ((f16x2*)vT)[((size_t)(d0 + d) * N + n0) / 2 + j] = hh;
  }
}

// ---------------------------------------------------------------- fused MFMA flash attention, rel shared across heads
// 4 waves = 4 heads. Per group of 4 m-tiles: wave w computes rel tile (g*4+w) once (8 mfma),
// exchanges C-fragments via LDS (4 float4-planes, conflict-free), then every wave does only
// 2 QK + 2 PV mfma per tile. Identical f32 accumulation order as fused version -> same numerics.
__global__ __launch_bounds__(256, 4) void k_attn2(const f16* __restrict__ qh, const f16* __restrict__ kh,
    const f16* __restrict__ vTh, const f16* __restrict__ sch, const f16* __restrict__ scSh,
    float* __restrict__ pacc, float* __restrict__ pl) {
  __shared__ float relbuf[4 * 4 * 64 * 4];   // [tile][reg4-plane][lane][4] = 16KB
  int tid = threadIdx.x, w = tid >> 6, lane = tid & 63, lrow = lane & 31, lhalf = lane >> 5;
  int n0 = blockIdx.x * 32, ntile = blockIdx.x, chunk = blockIdx.y;
  const f16* qp = qh + (size_t)(n0 + lrow) * HID + 32 * w + lhalf * 8;
  f16x8 qb0 = *(const f16x8*)(qp);
  f16x8 qb1 = *(const f16x8*)(qp + 16);
  f32x16 oacc = {0,0,0,0,0,0,0,0,0,0,0,0,0,0,0,0};
  float l = 0.f;
  for (int g = 0; g < NGRP; ++g) {
    // my rel tile: m-tile g*4+w
    int m0my = chunk * CHUNKM + (g * 4 + w) * 32;
    f32x16 rs = {0,0,0,0,0,0,0,0,0,0,0,0,0,0,0,0};
#pragma unroll
    for (int ks = 0; ks < 8; ++ks) {
      f16x8 as = *(const f16x8*)(scSh + (size_t)(m0my + lrow) * HID + ks * 16 + lhalf * 8);
      f16x8 bs = *(const f16x8*)(sch + (size_t)(n0 + lrow) * HID + ks * 16 + lhalf * 8);
      rs = __builtin_amdgcn_mfma_f32_32x32x16_f16(as, bs, rs, 0, 0, 0);
    }
    __syncthreads();   // previous group's reads complete before overwrite
    {
      int base = w * 1024 + lane * 4;
      *(float4*)&relbuf[base +   0] = make_float4(rs[0],  rs[1],  rs[2],  rs[3]);
      *(float4*)&relbuf[base + 256] = make_float4(rs[4],  rs[5],  rs[6],  rs[7]);
      *(float4*)&relbuf[base + 512] = make_float4(rs[8],  rs[9],  rs[10], rs[11]);
      *(float4*)&relbuf[base + 768] = make_float4(rs[12], rs[13], rs[14], rs[15]);
    }
    __syncthreads();
#pragma unroll
    for (int t = 0; t < 4; ++t) {
      int m0 = chunk * CHUNKM + (g * 4 + t) * 32;
      f32x16 sacc;
      {
        int base = t * 1024 + lane * 4;
        float4 r0 = *(const float4*)&relbuf[base +   0];
        float4 r1 = *(const float4*)&relbuf[base + 256];
        float4 r2 = *(const float4*)&relbuf[base + 512];
        float4 r3 = *(const float4*)&relbuf[base + 768];
        sacc[0]=r0.x;  sacc[1]=r0.y;  sacc[2]=r0.z;  sacc[3]=r0.w;
        sacc[4]=r1.x;  sacc[5]=r1.y;  sacc[6]=r1.z;  sacc[7]=r1.w;
        sacc[8]=r2.x;  sacc[9]=r2.y;  sacc[10]=r2.z; sacc[11]=r2.w;
        sacc[12]=r3.x; sacc[13]=r3.y; sacc[14]=r3.z; sacc[15]=r3.w;
      }
      const f16* kp = kh + (size_t)(m0 + lrow) * HID + 32 * w + lhalf * 8;
      f16x8 ka0 = *(const f16x8*)(kp);
      f16x8 ka1 = *(const f16x8*)(kp + 16);
      const f16* vp = vTh + (size_t)(32 * w + lrow) * N + m0 + lhalf * 8;
      f16x8 va0 = *(const f16x8*)(vp);
      f16x8 va1 = *(const f16x8*)(vp + 16);
      sacc = __builtin_amdgcn_mfma_f32_32x32x16_f16(ka0, qb0, sacc, 0, 0, 0);
      sacc = __builtin_amdgcn_mfma_f32_32x32x16_f16(ka1, qb1, sacc, 0, 0, 0);
      // fixed-shift softmax + in-register P->B-frag packing
      uint w0[2], w1[2], w2[2], w3[2];
#pragma unroll
      for (int ks = 0; ks < 2; ++ks) {
        float p[8];
#pragma unroll
        for (int i = 0; i < 8; ++i)
          p[i] = exp2f(fmaf(sacc[ks * 8 + i], LOG2E, SH2));
        uint Wa = __builtin_bit_cast(uint, __builtin_amdgcn_cvt_pkrtz(p[0], p[1]));
        uint Wb = __builtin_bit_cast(uint, __builtin_amdgcn_cvt_pkrtz(p[2], p[3]));
        uint Wc = __builtin_bit_cast(uint, __builtin_amdgcn_cvt_pkrtz(p[4], p[5]));
        uint Wd = __builtin_bit_cast(uint, __builtin_amdgcn_cvt_pkrtz(p[6], p[7]));
        {
          f16x2 ha = __builtin_bit_cast(f16x2, Wa), hb = __builtin_bit_cast(f16x2, Wb);
          f16x2 hc = __builtin_bit_cast(f16x2, Wc), hd = __builtin_bit_cast(f16x2, Wd);
          l += (float)ha[0] + (float)ha[1] + (float)hb[0] + (float)hb[1]
             + (float)hc[0] + (float)hc[1] + (float)hd[0] + (float)hd[1];
        }
        uint Wax = (uint)__shfl_xor((int)Wa, 32, 64);
        uint Wbx = (uint)__shfl_xor((int)Wb, 32, 64);
        uint Wcx = (uint)__shfl_xor((int)Wc, 32, 64);
        uint Wdx = (uint)__shfl_xor((int)Wd, 32, 64);
        bool hi = (lhalf != 0);
        w0[ks] = hi ? Wcx : Wa;
        w1[ks] = hi ? Wdx : Wb;
        w2[ks] = hi ? Wc : Wax;
        w3[ks] = hi ? Wd : Wbx;
      }
      f16x8 pb0 = __builtin_bit_cast(f16x8, make_uint4(w0[0], w1[0], w2[0], w3[0]));
      f16x8 pb1 = __builtin_bit_cast(f16x8, make_uint4(w0[1], w1[1], w2[1], w3[1]));
      oacc = __builtin_amdgcn_mfma_f32_32x32x16_f16(va0, pb0, oacc, 0, 0, 0);
      oacc = __builtin_amdgcn_mfma_f32_32x32x16_f16(va1, pb1, oacc, 0, 0, 0);
    }
  }
  l += __shfl_xor(l, 32, 64);
  float* pp = pacc + ((size_t)(chunk * 4 + w) * 128 + ntile) * 1024 + lane * 16;
  *(float4*)(pp +  0) = make_float4(oacc[0],  oacc[1],  oacc[2],  oacc[3]);
  *(float4*)(pp +  4) = make_float4(oacc[4],  oacc[5],  oacc[6],  oacc[7]);
  *(float4*)(pp +  8) = make_float4(oacc[8],  oacc[9],  oacc[10], oacc[11]);
  *(float4*)(pp + 12) = make_float4(oacc[12], oacc[13], oacc[14], oacc[15]);
  if (lane < 32) pl[(size_t)(chunk * 4 + w) * N + n0 + lrow] = l;
}

// ---------------------------------------------------------------- merge 8 m-chunks (fixed shift -> plain sums)
__global__ __launch_bounds__(256) void k_attn_merge2(const float* __restrict__ pacc,
    const float* __restrict__ pl, float* __restrict__ attno) {
  __shared__ float ao[32][132];
  int tid = threadIdx.x, h = tid >> 6, lane = tid & 63, lrow = lane & 31, lhalf = lane >> 5;
  int ntile = blockIdx.x, n0 = ntile * 32;
  float o[16];
#pragma unroll
  for (int r = 0; r < 16; ++r) o[r] = 0.f;
  float l = 0.f;
#pragma unroll
  for (int c = 0; c < NCHUNK; ++c) {
    const float* pp = pacc + ((size_t)(c * 4 + h) * 128 + ntile) * 1024 + lane * 16;
    float4 r0 = *(const float4*)(pp), r1 = *(const float4*)(pp + 4);
    float4 r2 = *(const float4*)(pp + 8), r3 = *(const float4*)(pp + 12);
    o[0]+=r0.x; o[1]+=r0.y; o[2]+=r0.z; o[3]+=r0.w;
    o[4]+=r1.x; o[5]+=r1.y; o[6]+=r1.z; o[7]+=r1.w;
    o[8]+=r2.x; o[9]+=r2.y; o[10]+=r2.z; o[11]+=r2.w;
    o[12]+=r3.x; o[13]+=r3.y; o[14]+=r3.z; o[15]+=r3.w;
    l += pl[(size_t)(c * 4 + h) * N + n0 + lrow];
  }
  float inv = 1.0f / l;
#pragma unroll
  for (int r = 0; r < 16; ++r) {
    int d = (r & 3) + 8 * (r >> 2) + 4 * lhalf;   // C-layout row
    ao[lrow][h * 32 + d] = o[r] * inv;
  }
  __syncthreads();
  for (int i = tid; i < 32 * 32; i += 256) {
    int row = i >> 5, c4 = i & 31;
    *(float4*)(attno + (size_t)(n0 + row) * HID + c4 * 4) = *(float4*)&ao[row][c4 * 4];
  }
}

// ---------------------------------------------------------------- FFN fused (8 rows/block)
__global__ __launch_bounds__(256) void k_ffn(const float* __restrict__ fln,
    const float* __restrict__ w1, const float* __restrict__ b1,
    const float* __restrict__ w2, const float* __restrict__ b2,
    const float* __restrict__ eig, float* __restrict__ out) {
  __shared__ float fs[8][HID];
  __shared__ float t1[8][FF];
  int r0 = blockIdx.x * 8, tid = threadIdx.x;
  {
    int rr = tid >> 5, c4 = tid & 31;
    ((float4*)fs[rr])[c4] = *(const float4*)(fln + (size_t)(r0 + rr) * HID + c4 * 4);
  }
  __syncthreads();
  {
    float acc[8];
#pragma unroll
    for (int i = 0; i < 8; ++i) acc[i] = b1[tid];
    for (int k2 = 0; k2 < HID; ++k2) {
      float wv = w1[k2 * FF + tid];
#pragma unroll
      for (int i = 0; i < 8; ++i) acc[i] += fs[i][k2] * wv;
    }
#pragma unroll
    for (int i = 0; i < 8; ++i) {
      float xg = acc[i];
      t1[i][tid] = 0.5f * xg * (1.0f + erff(xg * 0.7071067811865476f));
    }
  }
  __syncthreads();
  int c = tid & 127, rb = tid >> 7;
  float acc2[4];
#pragma unroll
  for (int i = 0; i < 4; ++i) acc2[i] = b2[c];
  for (int k2 = 0; k2 < FF; ++k2) {
    float wv = w2[k2 * HID + c];
#pragma unroll
    for (int i = 0; i < 4; ++i) acc2[i] += t1[rb + 2 * i][k2] * wv;
  }
#pragma unroll
  for (int i = 0; i < 4; ++i) {
    int rr = r0 + rb + 2 * i;
    out[(size_t)rr * HID + c] = acc2[i] + eig[(size_t)rr * HID + c];
  }
}

// ---------------------------------------------------------------- decoder (16 rows/block, split-k)
__global__ __launch_bounds__(256) void k_dec(const float* __restrict__ eig2,
    const float* __restrict__ dw, const float* __restrict__ db, float* __restrict__ newe) {
  int tid = threadIdx.x;
  int r = tid >> 4, j = (tid >> 2) & 3, q = tid & 3;
  int n = blockIdx.x * 16 + r;
  const float* ep = eig2 + (size_t)n * HID + q * 32;
  float a = 0.f;
#pragma unroll
  for (int t4 = 0; t4 < 8; ++t4) {
    float4 e4 = *(const float4*)(ep + t4 * 4);
    int k0 = q * 32 + t4 * 4;
    a += e4.x * dw[k0 * NHEAD + j] + e4.y * dw[(k0 + 1) * NHEAD + j]
       + e4.z * dw[(k0 + 2) * NHEAD + j] + e4.w * dw[(k0 + 3) * NHEAD + j];
  }
  a += __shfl_down(a, 1, 64);
  a += __shfl_down(a, 2, 64);
  if (q == 0) newe[n * NHEAD + j] = db[j] + a;
}

// ---------------------------------------------------------------- utx partials: u^T @ h, n-split 32
__global__ __launch_bounds__(256) void k_utx(const float* __restrict__ u,
    const float* __restrict__ h, float* __restrict__ putx) {
  __shared__ float hs[128][NC];   // 8KB
  int tid = threadIdx.x;
  int m = blockIdx.x * 256 + tid;
  int n0 = blockIdx.y * 128;
  for (int i = tid; i < 128 * 4; i += 256) {
    int row = i >> 2, cq = i & 3;
    ((float4*)hs[row])[cq] = *(const float4*)(h + (size_t)(n0 + row) * NC + cq * 4);
  }
  __syncthreads();
  float acc[16];
#pragma unroll
  for (int c = 0; c < 16; ++c) acc[c] = 0.f;
  for (int nb = 0; nb < 16; ++nb) {
    float uv[8];
#pragma unroll
    for (int t = 0; t < 8; ++t)
      uv[t] = u[(size_t)(n0 + nb * 8 + t) * N + m];
#pragma unroll
    for (int t = 0; t < 8; ++t) {
      int nl = nb * 8 + t;
      float4 h0 = ((const float4*)hs[nl])[0];
      float4 h1 = ((const float4*)hs[nl])[1];
      float4 h2 = ((const float4*)hs[nl])[2];
      float4 h3 = ((const float4*)hs[nl])[3];
      acc[0]  += uv[t] * h0.x;  acc[1]  += uv[t] * h0.y;
      acc[2]  += uv[t] * h0.z;  acc[3]  += uv[t] * h0.w;
      acc[4]  += uv[t] * h1.x;  acc[5]  += uv[t] * h1.y;
      acc[6]  += uv[t] * h1.z;  acc[7]  += uv[t] * h1.w;
      acc[8]  += uv[t] * h2.x;  acc[9]  += uv[t] * h2.y;
      acc[10] += uv[t] * h2.z;  acc[11] += uv[t] * h2.w;
      acc[12] += uv[t] * h3.x;  acc[13] += uv[t] * h3.y;
      acc[14] += uv[t] * h3.z;  acc[15] += uv[t] * h3.w;
    }
  }
  float* o = putx + ((size_t)blockIdx.y * N + m) * NC;
  *(float4*)(o +  0) = make_float4(acc[0],  acc[1],  acc[2],  acc[3]);
  *(float4*)(o +  4) = make_float4(acc[4],  acc[5],  acc[6],  acc[7]);
  *(float4*)(o +  8) = make_float4(acc[8],  acc[9],  acc[10], acc[11]);
  *(float4*)(o + 12) = make_float4(acc[12], acc[13], acc[14], acc[15]);
}

// ---------------------------------------------------------------- s build: sum partials, scale, output TRANSPOSED sT[16][N]
__global__ __launch_bounds__(256) void k_sbuild(const float* __restrict__ putx,
    const float* __restrict__ newe, const float* __restrict__ specw,
    float* __restrict__ sT) {
  int i = blockIdx.x * 256 + threadIdx.x;   // (m, cq)
  int m = i >> 2, cq = i & 3;
  float4 t = make_float4(0.f, 0.f, 0.f, 0.f);
#pragma unroll 8
  for (int ch = 0; ch < NSPLIT; ++ch) {
    float4 p = *(const float4*)(putx + ((size_t)ch * N + m) * NC + cq * 4);
    t.x += p.x; t.y += p.y; t.z += p.z; t.w += p.w;
  }
  float4 ne = *(const float4*)(newe + (size_t)m * NHEAD);
  float fac[4];
#pragma unroll
  for (int cc = 0; cc < 4; ++cc) {
    int c = cq * 4 + cc;
    fac[cc] = ne.x * specw[1 * NC + c] + ne.y * specw[2 * NC + c]
            + ne.z * specw[3 * NC + c] + ne.w * specw[4 * NC + c];
  }
  sT[(size_t)(cq * 4 + 0) * N + m] = t.x * fac[0];
  sT[(size_t)(cq * 4 + 1) * N + m] = t.y * fac[1];
  sT[(size_t)(cq * 4 + 2) * N + m] = t.z * fac[2];
  sT[(size_t)(cq * 4 + 3) * N + m] = t.w * fac[3];
}

// ---------------------------------------------------------------- u @ s partials: 16 rows/block, m-split 2
__global__ __launch_bounds__(256) void k_final(const float* __restrict__ u,
    const float* __restrict__ sT, float* __restrict__ pfin) {
  __shared__ float sTl[16][256];   // 16KB
  int tid = threadIdx.x, w = tid >> 6, lane = tid & 63;
  int r0 = blockIdx.x * 16;
  size_t mbase = (size_t)blockIdx.y * 2048;
  float a[4][16];
#pragma unroll
  for (int r = 0; r < 4; ++r)
#pragma unroll
    for (int c = 0; c < 16; ++c) a[r][c] = 0.f;
  for (int chunk = 0; chunk < 8; ++chunk) {
    size_t mc0 = mbase + chunk * 256;
    __syncthreads();
    for (int i = tid; i < 16 * 64; i += 256) {
      int c = i >> 6, q = i & 63;
      ((float4*)&sTl[c][0])[q] = *(const float4*)(sT + (size_t)c * N + mc0 + q * 4);
    }
    __syncthreads();
    float4 u4[4];
#pragma unroll
    for (int r = 0; r < 4; ++r)
      u4[r] = *(const float4*)(u + (size_t)(r0 + w * 4 + r) * N + mc0 + 4 * lane);
#pragma unroll
    for (int c = 0; c < 16; ++c) {
      float4 sv = *(const float4*)&sTl[c][4 * lane];
#pragma unroll
      for (int r = 0; r < 4; ++r)
        a[r][c] += u4[r].x * sv.x + u4[r].y * sv.y + u4[r].z * sv.z + u4[r].w * sv.w;
    }
  }
#pragma unroll
  for (int off = 32; off > 0; off >>= 1)
#pragma unroll
    for (int r = 0; r < 4; ++r)
#pragma unroll
      for (int c = 0; c < 16; ++c)
        a[r][c] += __shfl_xor(a[r][c], off, 64);
  if (lane == 0) {
#pragma unroll
    for (int r = 0; r < 4; ++r) {
      float* op = pfin + ((size_t)blockIdx.y * N + r0 + w * 4 + r) * NC;
      *(float4*)(op +  0) = make_float4(a[r][0],  a[r][1],  a[r][2],  a[r][3]);
      *(float4*)(op +  4) = make_float4(a[r][4],  a[r][5],  a[r][6],  a[r][7]);
      *(float4*)(op +  8) = make_float4(a[r][8],  a[r][9],  a[r][10], a[r][11]);
      *(float4*)(op + 12) = make_float4(a[r][12], a[r][13], a[r][14], a[r][15]);
    }
  }
}

// ---------------------------------------------------------------- final merge: pfin halves + h*specw0
__global__ __launch_bounds__(256) void k_finmerge(const float* __restrict__ pfin,
    const float* __restrict__ h, const float* __restrict__ specw, float* __restrict__ out) {
  int i = blockIdx.x * 256 + threadIdx.x;   // quad id
  int n = i >> 2, cq = i & 3;
  float4 f0 = *(const float4*)(pfin + (size_t)n * NC + cq * 4);
  float4 f1 = *(const float4*)(pfin + ((size_t)N + n) * NC + cq * 4);
  float4 h4 = *(const float4*)(h + (size_t)n * NC + cq * 4);
  int c0 = cq * 4;
  float4 o;
  o.x = f0.x + f1.x + h4.x * specw[c0 + 0];
  o.y = f0.y + f1.y + h4.y * specw[c0 + 1];
  o.z = f0.z + f1.z + h4.z * specw[c0 + 2];
  o.w = f0.w + f1.w + h4.w * specw[c0 + 3];
  *(float4*)(out + (size_t)n * NC + cq * 4) = o;
}

// ================================================================ launcher
extern "C" void kernel_launch(void* const* d_in, const int* in_sizes, int n_in,
                              void* d_out, int out_size, void* d_ws, size_t ws_size,
                              hipStream_t stream) {
  const float* e    = (const float*)d_in[0];
  const float* u    = (const float*)d_in[1];
  const float* x    = (const float*)d_in[2];
  const float* few1 = (const float*)d_in[3];
  const float* feb1 = (const float*)d_in[4];
  const float* few2 = (const float*)d_in[5];
  const float* feb2 = (const float*)d_in[6];
  const float* eww  = (const float*)d_in[7];
  const float* ewb  = (const float*)d_in[8];
  const float* ln1g = (const float*)d_in[9];
  const float* ln1b = (const float*)d_in[10];
  const float* wq   = (const float*)d_in[11];
  const float* bq   = (const float*)d_in[12];
  const float* wk   = (const float*)d_in[13];
  const float* bk   = (const float*)d_in[14];
  const float* wv_  = (const float*)d_in[15];
  const float* bv   = (const float*)d_in[16];
  const float* wo   = (const float*)d_in[17];
  const float* bo   = (const float*)d_in[18];
  const float* ln2g = (const float*)d_in[19];
  const float* ln2b = (const float*)d_in[20];
  const float* fw1  = (const float*)d_in[21];
  const float* fb1  = (const float*)d_in[22];
  const float* fw2  = (const float*)d_in[23];
  const float* fb2  = (const float*)d_in[24];
  const float* dw   = (const float*)d_in[25];
  const float* db   = (const float*)d_in[26];
  const float* spw  = (const float*)d_in[27];
  float* out = (float*)d_out;

  char* wsb = (char*)d_ws;
  auto alloc = [&](size_t bytes) { char* p = wsb; wsb += (bytes + 1023) & ~(size_t)1023; return p; };
  float* h    = (float*)alloc(N * NC * 4);
  f16*  sc_h  = (f16*)alloc(N * HID * 2);
  f16*  scS_h = (f16*)alloc(N * HID * 2);
  float* eigw = (float*)alloc(N * HID * 4);
  float* mln  = (float*)alloc(N * HID * 4);
  f16*  q_h   = (f16*)alloc(N * HID * 2);
  f16*  k_h   = (f16*)alloc(N * HID * 2);
  float* v    = (float*)alloc(N * HID * 4);
  f16*  vT_h  = (f16*)alloc(N * HID * 2);
  float* attno= (float*)alloc(N * HID * 4);
  float* eig  = (float*)alloc(N * HID * 4);
  float* fln  = (float*)alloc(N * HID * 4);
  float* eig2 = (float*)alloc(N * HID * 4);
  float* newe = (float*)alloc(N * NHEAD * 4);
  float* sT   = (float*)alloc((size_t)NC * N * 4);
  float* putx = (float*)alloc((size_t)NSPLIT * N * NC * 4);
  float* pacc = (float*)alloc((size_t)NCHUNK * 4 * 128 * 1024 * 4);
  float* pl   = (float*)alloc((size_t)NCHUNK * 4 * N * 4);
  float* pfin = (float*)alloc((size_t)2 * N * NC * 4);

  k_feat<<<N / 8, 256, 0, stream>>>(x, few1, feb1, few2, feb2, h);
  k_utx<<<dim3(N / 256, NSPLIT), 256, 0, stream>>>(u, h, putx);
  k_sine_eigw<<<N / 8, 256, 0, stream>>>(e, eww, ewb, sc_h, scS_h, eigw);
  k_ln<<<N / 4, 256, 0, stream>>>(eigw, ln1g, ln1b, mln);
  k_lin128<false, true><<<N / 8, 256, 0, stream>>>(mln, wq, bq, nullptr, nullptr, q_h, SCALE);
  k_lin128<false, true><<<N / 8, 256, 0, stream>>>(mln, wk, bk, nullptr, nullptr, k_h, 1.0f);
  k_lin128<false, false><<<N / 8, 256, 0, stream>>>(mln, wv_, bv, nullptr, v, nullptr, 1.0f);
  k_vT<<<dim3(N / 64, 4), 256, 0, stream>>>(v, vT_h);
  k_attn2<<<dim3(128, NCHUNK), 256, 0, stream>>>(q_h, k_h, vT_h, sc_h, scS_h, pacc, pl);
  k_attn_merge2<<<128, 256, 0, stream>>>(pacc, pl, attno);
  k_lin128<true, false><<<N / 8, 256, 0, stream>>>(attno, wo, bo, eigw, eig, nullptr, 1.0f);
  k_ln<<<N / 4, 256, 0, stream>>>(eig, ln2g, ln2b, fln);
  k_ffn<<<N / 8, 256, 0, stream>>>(fln, fw1, fb1, fw2, fb2, eig, eig2);
  k_dec<<<N / 16, 256, 0, stream>>>(eig2, dw, db, newe);
  k_sbuild<<<N * 4 / 256, 256, 0, stream>>>(putx, newe, spw, sT);
  k_final<<<dim3(N / 16, 2), 256, 0, stream>>>(u, sT, pfin);
  k_finmerge<<<N * 4 / 256, 256, 0, stream>>>(pfin, h, spw, out);
}